// Round 1
// baseline (560.998 us; speedup 1.0000x reference)
//
#include <hip/hip_runtime.h>
#include <hip/hip_fp8.h>
#include <cstdint>
#include <cstddef>

typedef __attribute__((ext_vector_type(4))) float f32x4;
typedef __attribute__((ext_vector_type(8))) int i32x8;

#define DEVINL __device__ __forceinline__

DEVINL unsigned short f2bf(float f){
  union { float f; unsigned u; } v; v.f = f;
  unsigned r = v.u + 0x7fffu + ((v.u >> 16) & 1u);  // RNE
  return (unsigned short)(r >> 16);
}
DEVINL float bf2f(unsigned short h){
  union { unsigned u; float f; } v; v.u = ((unsigned)h) << 16;
  return v.f;
}
DEVINL unsigned char f2fp8(float f){
  __hip_fp8_e4m3 t(f);           // OCP e4m3fn, saturating
  return (unsigned char)t.__x;
}
DEVINL void gload_lds16(const void* g, void* l){
  __builtin_amdgcn_global_load_lds((const __attribute__((address_space(1))) void*)g,
                                   (__attribute__((address_space(3))) void*)l, 16, 0, 0);
}

// scale constants: activations stored x2^6, weights x2^4; descale via e8m0 MFMA scales
#define ACT_SCALE 64.0f
#define W_SCALE   16.0f
#define E8M0_ACT  121   // 2^-6
#define E8M0_W    123   // 2^-4

// ---- weight prep: Wt[n][k] = fp8(W[k][n] * 16) ----
__global__ __launch_bounds__(256) void transpose_fp8(
    const float* __restrict__ W, unsigned char* __restrict__ Wt, int K, int N)
{
  __shared__ unsigned char tile[32][33];
  int k0 = blockIdx.x * 32, n0 = blockIdx.y * 32;
  int tx = threadIdx.x & 31, ty = threadIdx.x >> 5;
  #pragma unroll
  for (int i = 0; i < 4; ++i) {
    int k = k0 + ty + 8*i, n = n0 + tx;
    tile[ty + 8*i][tx] = f2fp8(W[(size_t)k*N + n] * W_SCALE);
  }
  __syncthreads();
  #pragma unroll
  for (int i = 0; i < 4; ++i) {
    int n = n0 + ty + 8*i, k = k0 + tx;
    Wt[(size_t)n*K + k] = tile[tx][ty + 8*i];
  }
}

// ---- L1 prep: compact knn mask column j -> 21 packed (idx<<16 | bf16(W1)) ----
__global__ __launch_bounds__(256) void build_sparse(
    const float* __restrict__ C1, const float* __restrict__ W1,
    unsigned* __restrict__ packed)
{
  const int j = blockIdx.x;            // 0..195
  const int w = threadIdx.x >> 6, l = threadIdx.x & 63;
  __shared__ int wcnt[4], wbase[4];
  int cnt = 0;
  #pragma unroll 4
  for (int it = 0; it < 16; ++it) {
    int k = w*1024 + it*64 + l;
    float c = C1[(size_t)k*196 + j];
    unsigned long long m = __ballot(c != 0.f);
    cnt += (int)__popcll(m);
  }
  if (l == 0) wcnt[w] = cnt;
  __syncthreads();
  if (threadIdx.x < 21) packed[j*21 + threadIdx.x] = 0;  // safety vs poison
  if (threadIdx.x == 0) {
    int b = 0;
    #pragma unroll
    for (int i = 0; i < 4; ++i) { wbase[i] = b; b += wcnt[i]; }
  }
  __syncthreads();
  int base = wbase[w];
  #pragma unroll 4
  for (int it = 0; it < 16; ++it) {
    int k = w*1024 + it*64 + l;
    float c = C1[(size_t)k*196 + j];
    unsigned long long m = __ballot(c != 0.f);
    if (c != 0.f) {
      int pos = base + (int)__popcll(m & ((1ull << l) - 1ull));
      if (pos < 21)
        packed[j*21 + pos] = ((unsigned)k << 16)
                           | (unsigned)f2bf(W1[(size_t)k*196 + j] * c);
    }
    base += (int)__popcll(m);
  }
}

// ---- L1: h1 = relu(x @ sparse(W1*C1) + b1), 2 rows/block, x read exactly once ----
__global__ __launch_bounds__(256) void layer1_sparse(
    const float* __restrict__ x, const unsigned* __restrict__ packed,
    const float* __restrict__ b1, unsigned short* __restrict__ h1)
{
  __shared__ float xs[2*4096];
  const int t = threadIdx.x;
  const long m0 = (long)blockIdx.x * 2;
  const float4* src = (const float4*)(x + m0*4096);
  #pragma unroll
  for (int i = 0; i < 8; ++i) ((float4*)xs)[t + i*256] = src[t + i*256];
  __syncthreads();
  for (int e = t; e < 2*196; e += 256) {
    int row = (e >= 196) ? 1 : 0;
    int col = e - row*196;
    const float* xr = xs + row*4096;
    float acc = b1[col];
    #pragma unroll
    for (int i = 0; i < 21; ++i) {
      unsigned p = packed[col*21 + i];
      acc += xr[p >> 16] * bf2f((unsigned short)(p & 0xffffu));
    }
    h1[(m0 + row)*256 + col] = f2bf(fmaxf(acc, 0.f));
  }
}

// ============================================================================
// MX-fp8 MFMA GEMM, 256x256 tile, BK=128, 8 waves (2M x 4N), double-buffered
// 128KB LDS, 4-phase counted-vmcnt schedule (T3+T4+T5 per 8-phase template).
//
// LDS layout (per 32KB tile, per 16-row block of 2KB):
//   chunk c (16B) of row r: rblk=r>>4, h=c&1, q=c>>1, rloc=r&15
//   offset = rblk*2048 + h*1024 + (q*16 + rloc)*16
// => fragment read by lane (q=lane>>4, l16=lane&15) at row base+l16 is exactly
//    base + lane*16 (v0) and +1024 (v1): lane-stride-16 contiguous, 0 bank
//    conflicts. gload_lds dest stays LINEAR (seg*16); the layout inverse is
//    applied to the per-lane GLOBAL source address (G21: both-sides).
//
// Staging order per K-tile (8 rounds of 512 segs = 64 rows):
//   P0: B-q0,B-q1   P1: B-q2,B-q3   P2: A-q0,A-q2   P3: A-q1,A-q3
// (A quarters ordered so phases 0/1 of both wm groups need only first 6 rounds)
// Waits (counted, never 0 mid-loop):
//   P1: vmcnt(4)  -> retires prev tile's A-q1,A-q3 before P2/P3 reads
//   P3: vmcnt(2)  -> retires next tile's first 6 rounds before its P0/P1 reads
// ============================================================================

#define MXMFMA(va, vb, c) __builtin_amdgcn_mfma_scale_f32_16x16x128_f8f6f4( \
    (va), (vb), (c), 0, 0, 0, E8M0_ACT, 0, E8M0_W)

#define MFMA8(I, va0, va1) \
  acc[(I)][0]   = MXMFMA(va0, b0, acc[(I)][0]); \
  acc[(I)][1]   = MXMFMA(va0, b1, acc[(I)][1]); \
  acc[(I)][2]   = MXMFMA(va0, b2, acc[(I)][2]); \
  acc[(I)][3]   = MXMFMA(va0, b3, acc[(I)][3]); \
  acc[(I)+1][0] = MXMFMA(va1, b0, acc[(I)+1][0]); \
  acc[(I)+1][1] = MXMFMA(va1, b1, acc[(I)+1][1]); \
  acc[(I)+1][2] = MXMFMA(va1, b2, acc[(I)+1][2]); \
  acc[(I)+1][3] = MXMFMA(va1, b3, acc[(I)+1][3]);

template<int ACT>
__global__ __launch_bounds__(512, 2) void gemm_fp8_8ph(
    const unsigned char* __restrict__ A, const unsigned char* __restrict__ Bt,
    const float* __restrict__ bias, void* __restrict__ Cptr, int K, int ldC)
{
  constexpr int BM = 256, BN = 256;
  extern __shared__ unsigned char sm[];
  const int tid  = threadIdx.x;
  const int lane = tid & 63;
  const int w    = tid >> 6;
  const int wm = w >> 2, wn = w & 3;          // 2M x 4N wave grid
  const int q = lane >> 4, l16 = lane & 15;
  const long m0 = (long)blockIdx.x * BM;
  const long n0 = (long)blockIdx.y * BN;

  unsigned char* Ac = sm;                      // 32KB
  unsigned char* Bc = sm + 32768;
  unsigned char* An = sm + 65536;
  unsigned char* Bn = sm + 98304;

  f32x4 acc[8][4] = {};
  const int NT = K >> 7;

  // stage one quarter (512 segs = 64 rows): linear LDS dest, inverse-layout src
  auto stageA = [&](unsigned char* Ld, int qr, int kk) {
    int seg  = qr*512 + tid;
    int rblk = seg >> 7, ci = seg & 127;
    int h = ci >> 6, rem = ci & 63;
    int qq = rem >> 4, rloc = rem & 15;
    int r = rblk*16 + rloc, c = qq*2 + h;
    gload_lds16(A + (m0 + r)*(long)K + kk + c*16, Ld + seg*16);
  };
  auto stageB = [&](unsigned char* Ld, int qr, int kk) {
    int seg  = qr*512 + tid;
    int rblk = seg >> 7, ci = seg & 127;
    int h = ci >> 6, rem = ci & 63;
    int qq = rem >> 4, rloc = rem & 15;
    int r = rblk*16 + rloc, c = qq*2 + h;
    gload_lds16(Bt + (n0 + r)*(long)K + kk + c*16, Ld + seg*16);
  };
  // read one 16x128 fragment (rblk = 16-row block index): conflict-free
  auto rdfrag = [&](const unsigned char* Ld, int rblk) -> i32x8 {
    union { uint4 v[2]; i32x8 f; } u;
    const unsigned char* p = Ld + rblk*2048 + lane*16;
    u.v[0] = *(const uint4*)p;
    u.v[1] = *(const uint4*)(p + 1024);
    return u.f;
  };

  // prologue: tile 0 fully staged
  #pragma unroll
  for (int qr = 0; qr < 4; ++qr) stageA(Ac, qr, 0);
  #pragma unroll
  for (int qr = 0; qr < 4; ++qr) stageB(Bc, qr, 0);
  asm volatile("s_waitcnt vmcnt(0)" ::: "memory");
  __builtin_amdgcn_s_barrier();

  for (int kt = 0; kt < NT; ++kt) {
    const bool haveNext = (kt + 1 < NT);
    const int kk = (kt + 1) << 7;
    i32x8 b0, b1, b2, b3;

    // ---- phase 0: B prefetch rounds 0,1; compute acc rows 0,1 ----
    if (haveNext) { stageB(Bn, 0, kk); stageB(Bn, 1, kk); }
    b0 = rdfrag(Bc, wn*4 + 0); b1 = rdfrag(Bc, wn*4 + 1);
    b2 = rdfrag(Bc, wn*4 + 2); b3 = rdfrag(Bc, wn*4 + 3);
    {
      i32x8 a0 = rdfrag(Ac, wm*8 + 0), a1 = rdfrag(Ac, wm*8 + 1);
      __builtin_amdgcn_s_barrier();
      asm volatile("s_waitcnt lgkmcnt(0)" ::: "memory");
      __builtin_amdgcn_sched_barrier(0);
      __builtin_amdgcn_s_setprio(1);
      MFMA8(0, a0, a1)
      __builtin_amdgcn_s_setprio(0);
      __builtin_amdgcn_s_barrier();
    }

    // ---- phase 1: B prefetch rounds 2,3; vmcnt(4); compute rows 2,3 ----
    if (haveNext) { stageB(Bn, 2, kk); stageB(Bn, 3, kk); }
    {
      i32x8 a0 = rdfrag(Ac, wm*8 + 2), a1 = rdfrag(Ac, wm*8 + 3);
      if (haveNext) { asm volatile("s_waitcnt vmcnt(4)" ::: "memory"); }
      else          { asm volatile("s_waitcnt vmcnt(0)" ::: "memory"); }
      __builtin_amdgcn_s_barrier();
      asm volatile("s_waitcnt lgkmcnt(0)" ::: "memory");
      __builtin_amdgcn_sched_barrier(0);
      __builtin_amdgcn_s_setprio(1);
      MFMA8(2, a0, a1)
      __builtin_amdgcn_s_setprio(0);
      __builtin_amdgcn_s_barrier();
    }

    // ---- phase 2: A prefetch quarters 0,2; compute rows 4,5 ----
    if (haveNext) { stageA(An, 0, kk); stageA(An, 2, kk); }
    {
      i32x8 a0 = rdfrag(Ac, wm*8 + 4), a1 = rdfrag(Ac, wm*8 + 5);
      __builtin_amdgcn_s_barrier();
      asm volatile("s_waitcnt lgkmcnt(0)" ::: "memory");
      __builtin_amdgcn_sched_barrier(0);
      __builtin_amdgcn_s_setprio(1);
      MFMA8(4, a0, a1)
      __builtin_amdgcn_s_setprio(0);
      __builtin_amdgcn_s_barrier();
    }

    // ---- phase 3: A prefetch quarters 1,3; vmcnt(2); compute rows 6,7 ----
    if (haveNext) { stageA(An, 1, kk); stageA(An, 3, kk); }
    {
      i32x8 a0 = rdfrag(Ac, wm*8 + 6), a1 = rdfrag(Ac, wm*8 + 7);
      if (haveNext) { asm volatile("s_waitcnt vmcnt(2)" ::: "memory"); }
      else          { asm volatile("s_waitcnt vmcnt(0)" ::: "memory"); }
      __builtin_amdgcn_s_barrier();
      asm volatile("s_waitcnt lgkmcnt(0)" ::: "memory");
      __builtin_amdgcn_sched_barrier(0);
      __builtin_amdgcn_s_setprio(1);
      MFMA8(6, a0, a1)
      __builtin_amdgcn_s_setprio(0);
      __builtin_amdgcn_s_barrier();
    }

    unsigned char* t;
    t = Ac; Ac = An; An = t;
    t = Bc; Bc = Bn; Bn = t;
  }

  // epilogue: D col = lane&15, row = (lane>>4)*4 + r  [m89/m91 layout]
  if constexpr (ACT == 0) {
    // relu -> fp8 x2^6, repack via LDS (stride 272 = 17x16: aligned, no 256-alias)
    __syncthreads();
    unsigned char* eb = sm;
    #pragma unroll
    for (int j = 0; j < 4; ++j) {
      int cl = wn*64 + j*16 + l16;
      float bv = bias[n0 + cl];
      #pragma unroll
      for (int i = 0; i < 8; ++i) {
        #pragma unroll
        for (int r = 0; r < 4; ++r) {
          int rl = wm*128 + i*16 + q*4 + r;
          eb[rl*272 + cl] = f2fp8(fmaxf(acc[i][j][r] + bv, 0.f) * ACT_SCALE);
        }
      }
    }
    __syncthreads();
    unsigned char* C = (unsigned char*)Cptr;
    #pragma unroll
    for (int it = 0; it < 8; ++it) {
      int seg = tid + it*512;           // 4096 segs: 256 rows x 16 chunks
      int row = seg >> 4, ch = seg & 15;
      *(uint4*)(C + (m0 + row)*(long)ldC + n0 + ch*16) =
          *(const uint4*)(eb + row*272 + ch*16);
    }
  } else {
    float* C = (float*)Cptr;
    #pragma unroll
    for (int j = 0; j < 4; ++j) {
      long col = n0 + wn*64 + j*16 + l16;
      float bv = bias[col];
      #pragma unroll
      for (int i = 0; i < 8; ++i) {
        #pragma unroll
        for (int r = 0; r < 4; ++r) {
          long row = m0 + wm*128 + i*16 + q*4 + r;
          float v = acc[i][j][r] + bv;
          C[row*(long)ldC + col] = 1.f / (1.f + __expf(-v));
        }
      }
    }
  }
}

// ---- fused L2+L3+L4+L5: h1[4 rows] -> d1 (fp8 x2^6), all intermediates in LDS ----
__global__ __launch_bounds__(256) void layer2345(
    const unsigned short* __restrict__ h1,
    const float* __restrict__ W2, const float* __restrict__ C2, const float* __restrict__ b2,
    const float* __restrict__ W3, const float* __restrict__ b3,
    const float* __restrict__ W4, const float* __restrict__ b4,
    const float* __restrict__ Wd1, const float* __restrict__ bd1,
    unsigned char* __restrict__ d1)
{
  __shared__ float h1s[4][200];
  __shared__ float h2s[4][10];
  __shared__ float h3s[4][1024];
  __shared__ float part[8][128];
  __shared__ float zs[4][32];
  const int t = threadIdx.x;
  const int w = t >> 6, l = t & 63;
  const long m0 = (long)blockIdx.x * 4;

  for (int e = t; e < 4*196; e += 256) {
    int row = e / 196, col = e - row*196;
    h1s[row][col] = bf2f(h1[(m0 + row)*256 + col]);
  }
  __syncthreads();

  {
    float acc[10];
    #pragma unroll
    for (int n = 0; n < 10; ++n) acc[n] = 0.f;
    #pragma unroll
    for (int it = 0; it < 4; ++it) {
      int k = l + it*64;
      if (k < 196) {
        float a = h1s[w][k];
        #pragma unroll
        for (int n = 0; n < 10; ++n) acc[n] += a * W2[k*10 + n] * C2[k*10 + n];
      }
    }
    #pragma unroll
    for (int off = 32; off > 0; off >>= 1) {
      #pragma unroll
      for (int n = 0; n < 10; ++n) acc[n] += __shfl_down(acc[n], off, 64);
    }
    if (l < 10) h2s[w][l] = fmaxf(acc[l] + b2[l], 0.f);
  }
  __syncthreads();

  #pragma unroll
  for (int jj = 0; jj < 4; ++jj) {
    int n = w*256 + jj*64 + l;
    float a0 = b3[n], a1 = a0, a2 = a0, a3 = a0;
    #pragma unroll
    for (int k = 0; k < 10; ++k) {
      float wv = W3[k*1024 + n];
      a0 += h2s[0][k]*wv; a1 += h2s[1][k]*wv;
      a2 += h2s[2][k]*wv; a3 += h2s[3][k]*wv;
    }
    h3s[0][n] = fmaxf(a0, 0.f); h3s[1][n] = fmaxf(a1, 0.f);
    h3s[2][n] = fmaxf(a2, 0.f); h3s[3][n] = fmaxf(a3, 0.f);
  }
  __syncthreads();

  {
    int n = t & 31, kg = t >> 5;
    float a0 = 0.f, a1 = 0.f, a2 = 0.f, a3 = 0.f;
    for (int k = kg*128; k < kg*128 + 128; ++k) {
      float wv = W4[k*32 + n];
      a0 += h3s[0][k]*wv; a1 += h3s[1][k]*wv;
      a2 += h3s[2][k]*wv; a3 += h3s[3][k]*wv;
    }
    part[kg][0*32 + n] = a0; part[kg][1*32 + n] = a1;
    part[kg][2*32 + n] = a2; part[kg][3*32 + n] = a3;
  }
  __syncthreads();
  if (t < 128) {
    float s = 0.f;
    #pragma unroll
    for (int kg = 0; kg < 8; ++kg) s += part[kg][t];
    zs[t >> 5][t & 31] = fmaxf(s + b4[t & 31], 0.f);
  }
  __syncthreads();

  #pragma unroll
  for (int jj = 0; jj < 4; ++jj) {
    int n = w*256 + jj*64 + l;
    float a0 = bd1[n], a1 = a0, a2 = a0, a3 = a0;
    #pragma unroll
    for (int k = 0; k < 32; ++k) {
      float wv = Wd1[k*1024 + n];
      a0 += zs[0][k]*wv; a1 += zs[1][k]*wv;
      a2 += zs[2][k]*wv; a3 += zs[3][k]*wv;
    }
    d1[(m0 + 0)*1024 + n] = f2fp8(fmaxf(a0, 0.f) * ACT_SCALE);
    d1[(m0 + 1)*1024 + n] = f2fp8(fmaxf(a1, 0.f) * ACT_SCALE);
    d1[(m0 + 2)*1024 + n] = f2fp8(fmaxf(a2, 0.f) * ACT_SCALE);
    d1[(m0 + 3)*1024 + n] = f2fp8(fmaxf(a3, 0.f) * ACT_SCALE);
  }
}

extern "C" void kernel_launch(void* const* d_in, const int* in_sizes, int n_in,
                              void* d_out, int out_size, void* d_ws, size_t ws_size,
                              hipStream_t stream)
{
  (void)in_sizes; (void)n_in; (void)out_size; (void)ws_size;
  const float* x   = (const float*)d_in[0];
  const float* C1  = (const float*)d_in[1];
  const float* W1  = (const float*)d_in[2];
  const float* b1  = (const float*)d_in[3];
  const float* C2  = (const float*)d_in[4];
  const float* W2  = (const float*)d_in[5];
  const float* b2  = (const float*)d_in[6];
  const float* W3  = (const float*)d_in[7];
  const float* b3  = (const float*)d_in[8];
  const float* W4  = (const float*)d_in[9];
  const float* b4  = (const float*)d_in[10];
  const float* Wd1 = (const float*)d_in[11];
  const float* bd1 = (const float*)d_in[12];
  const float* Wd2 = (const float*)d_in[13];
  const float* bd2 = (const float*)d_in[14];
  const float* Wd3 = (const float*)d_in[15];
  const float* bd3 = (const float*)d_in[16];
  float* out = (float*)d_out;

  char* ws = (char*)d_ws;
  size_t off = 0;
  auto alloc = [&](size_t bytes) -> void* {
    void* p = ws + off; off += (bytes + 255) & ~(size_t)255; return p;
  };
  unsigned char* Wt2 = (unsigned char*)alloc((size_t)2048*1024);   // Wd2^T fp8 x16
  unsigned char* Wt3 = (unsigned char*)alloc((size_t)4096*2048);   // Wd3^T fp8 x16
  unsigned*      pk  = (unsigned*)     alloc((size_t)196*21*4);    // packed sparse W1C1
  unsigned short* h1 = (unsigned short*)alloc((size_t)8192*256*2); // bf16
  unsigned char*  d1 = (unsigned char*) alloc((size_t)8192*1024);  // fp8 x2^6
  unsigned char*  d2 = (unsigned char*) alloc((size_t)8192*2048);  // fp8 x2^6

  // opt-in to 128KB dynamic LDS for the 8-phase GEMM (one-time, capture-safe)
  static int attr_set = 0;
  if (!attr_set) {
    hipFuncSetAttribute((const void*)gemm_fp8_8ph<0>,
                        hipFuncAttributeMaxDynamicSharedMemorySize, 131072);
    hipFuncSetAttribute((const void*)gemm_fp8_8ph<1>,
                        hipFuncAttributeMaxDynamicSharedMemorySize, 131072);
    attr_set = 1;
  }

  // prep
  build_sparse<<<dim3(196), 256, 0, stream>>>(C1, W1, pk);
  transpose_fp8<<<dim3(1024/32, 2048/32), 256, 0, stream>>>(Wd2, Wt2, 1024, 2048);
  transpose_fp8<<<dim3(2048/32, 4096/32), 256, 0, stream>>>(Wd3, Wt3, 2048, 4096);

  // L1: h1 = relu(x @ (W1*C1) + b1) — sparse gather, x read once
  layer1_sparse<<<dim3(8192/2), 256, 0, stream>>>(x, pk, b1, h1);
  // L2..L5 fused
  layer2345<<<dim3(8192/4), 256, 0, stream>>>(h1, W2, C2, b2, W3, b3, W4, b4,
                                              Wd1, bd1, d1);
  // L6: d2 = relu(d1 @ Wd2 + bd2)  M=8192 N=2048 K=1024  (MX-fp8, 256² 8-phase)
  gemm_fp8_8ph<0><<<dim3(8192/256, 2048/256), 512, 131072, stream>>>(
      d1, Wt2, bd2, d2, 1024, 2048);
  // L7: out = sigmoid(d2 @ Wd3 + bd3)  M=8192 N=4096 K=2048  (MX-fp8, 256² 8-phase)
  gemm_fp8_8ph<1><<<dim3(8192/256, 4096/256), 512, 131072, stream>>>(
      d2, Wt3, bd3, out, 2048, 4096);
}

// Round 2
// 537.258 us; speedup vs baseline: 1.0442x; 1.0442x over previous
//
#include <hip/hip_runtime.h>
#include <hip/hip_fp8.h>
#include <cstdint>
#include <cstddef>

typedef __attribute__((ext_vector_type(4))) float f32x4;
typedef __attribute__((ext_vector_type(8))) int i32x8;

#define DEVINL __device__ __forceinline__

DEVINL unsigned short f2bf(float f){
  union { float f; unsigned u; } v; v.f = f;
  unsigned r = v.u + 0x7fffu + ((v.u >> 16) & 1u);  // RNE
  return (unsigned short)(r >> 16);
}
DEVINL float bf2f(unsigned short h){
  union { unsigned u; float f; } v; v.u = ((unsigned)h) << 16;
  return v.f;
}
DEVINL unsigned char f2fp8(float f){
  __hip_fp8_e4m3 t(f);           // OCP e4m3fn, saturating
  return (unsigned char)t.__x;
}
DEVINL void gload_lds16(const void* g, void* l){
  __builtin_amdgcn_global_load_lds((const __attribute__((address_space(1))) void*)g,
                                   (__attribute__((address_space(3))) void*)l, 16, 0, 0);
}

// scale constants: activations stored x2^6, weights x2^4; descale via e8m0 MFMA scales
#define ACT_SCALE 64.0f
#define W_SCALE   16.0f
#define E8M0_ACT  121   // 2^-6
#define E8M0_W    123   // 2^-4

// ---- weight prep: Wt[n][k] = fp8(W[k][n] * 16) ----
__global__ __launch_bounds__(256) void transpose_fp8(
    const float* __restrict__ W, unsigned char* __restrict__ Wt, int K, int N)
{
  __shared__ unsigned char tile[32][33];
  int k0 = blockIdx.x * 32, n0 = blockIdx.y * 32;
  int tx = threadIdx.x & 31, ty = threadIdx.x >> 5;
  #pragma unroll
  for (int i = 0; i < 4; ++i) {
    int k = k0 + ty + 8*i, n = n0 + tx;
    tile[ty + 8*i][tx] = f2fp8(W[(size_t)k*N + n] * W_SCALE);
  }
  __syncthreads();
  #pragma unroll
  for (int i = 0; i < 4; ++i) {
    int n = n0 + ty + 8*i, k = k0 + tx;
    Wt[(size_t)n*K + k] = tile[tx][ty + 8*i];
  }
}

// ---- L1 prep: compact knn mask column j -> 21 packed (idx<<16 | bf16(W1)) ----
__global__ __launch_bounds__(256) void build_sparse(
    const float* __restrict__ C1, const float* __restrict__ W1,
    unsigned* __restrict__ packed)
{
  const int j = blockIdx.x;            // 0..195
  const int w = threadIdx.x >> 6, l = threadIdx.x & 63;
  __shared__ int wcnt[4], wbase[4];
  int cnt = 0;
  #pragma unroll 4
  for (int it = 0; it < 16; ++it) {
    int k = w*1024 + it*64 + l;
    float c = C1[(size_t)k*196 + j];
    unsigned long long m = __ballot(c != 0.f);
    cnt += (int)__popcll(m);
  }
  if (l == 0) wcnt[w] = cnt;
  __syncthreads();
  if (threadIdx.x < 21) packed[j*21 + threadIdx.x] = 0;  // safety vs poison
  if (threadIdx.x == 0) {
    int b = 0;
    #pragma unroll
    for (int i = 0; i < 4; ++i) { wbase[i] = b; b += wcnt[i]; }
  }
  __syncthreads();
  int base = wbase[w];
  #pragma unroll 4
  for (int it = 0; it < 16; ++it) {
    int k = w*1024 + it*64 + l;
    float c = C1[(size_t)k*196 + j];
    unsigned long long m = __ballot(c != 0.f);
    if (c != 0.f) {
      int pos = base + (int)__popcll(m & ((1ull << l) - 1ull));
      if (pos < 21)
        packed[j*21 + pos] = ((unsigned)k << 16)
                           | (unsigned)f2bf(W1[(size_t)k*196 + j] * c);
    }
    base += (int)__popcll(m);
  }
}

// ---- L1: h1 = relu(x @ sparse(W1*C1) + b1), 2 rows/block, x read exactly once ----
__global__ __launch_bounds__(256) void layer1_sparse(
    const float* __restrict__ x, const unsigned* __restrict__ packed,
    const float* __restrict__ b1, unsigned short* __restrict__ h1)
{
  __shared__ float xs[2*4096];
  const int t = threadIdx.x;
  const long m0 = (long)blockIdx.x * 2;
  const float4* src = (const float4*)(x + m0*4096);
  #pragma unroll
  for (int i = 0; i < 8; ++i) ((float4*)xs)[t + i*256] = src[t + i*256];
  __syncthreads();
  for (int e = t; e < 2*196; e += 256) {
    int row = (e >= 196) ? 1 : 0;
    int col = e - row*196;
    const float* xr = xs + row*4096;
    float acc = b1[col];
    #pragma unroll
    for (int i = 0; i < 21; ++i) {
      unsigned p = packed[col*21 + i];          // L1-hot 16.5 KB table
      acc += xr[p >> 16] * bf2f((unsigned short)(p & 0xffffu));
    }
    h1[(m0 + row)*256 + col] = f2bf(fmaxf(acc, 0.f));
  }
}

// ---- MX-fp8 MFMA GEMM: C = act(A[M,K] * Bt[N,K]^T + bias) ----
// 128x128 tile, BK=128, 2x2 waves, proven 2-phase structure (round-0 90us
// version) with the CONFLICT-FREE LDS layout verified in round 1 (0 conflict
// cycles measured):
//   chunk c (16B) of row r at: rblk*2048 + (c&1)*1024 + ((c>>1)*16 + (r&15))*16
//   (rblk = r>>4). Fragment read by lane = base + lane*16 and +1024 — lane-
//   contiguous 1KB, zero bank conflicts. gload_lds dest stays LINEAR (seg*16);
//   layout inverse applied to the per-lane GLOBAL source (G21 both-sides rule).
// Fragment content unchanged: lane holds k = q*32..q*32+31 (bitwise-identical
// accumulation vs the old (5g+r)&7 layout, which had 8-way read conflicts).
// ACT 0: relu -> fp8 x2^6 (LDS-repacked, stride 144, coalesced 16B stores);
// ACT 1: sigmoid -> fp32. Grid (M/128, N/128), 256 threads (2x2 waves).
template<int ACT>
__global__ __launch_bounds__(256) void gemm_fp8(
    const unsigned char* __restrict__ A, const unsigned char* __restrict__ Bt,
    const float* __restrict__ bias, void* __restrict__ Cptr, int K, int ldC)
{
  constexpr int BM = 128, BN = 128, BK = 128;
  constexpr int HM = 64, HN = 64, FM = 4, FN = 4;
  __shared__ __align__(16) unsigned char smem[32768];
  unsigned char* As = smem;
  unsigned char* Bs = smem + 16384;
  const int tid  = threadIdx.x;
  const int lane = tid & 63;
  const int w    = tid >> 6;
  const int wm = w & 1, wn = w >> 1;
  const int q = lane >> 4, l16 = lane & 15;
  const long m0 = (long)blockIdx.x * BM;
  const long n0 = (long)blockIdx.y * BN;

  f32x4 acc[FM][FN] = {};

  for (int k0 = 0; k0 < K; k0 += BK) {
    #pragma unroll
    for (int it = 0; it < 4; ++it) {
      int seg  = tid + it*256;
      int rblk = seg >> 7, ci = seg & 127;
      int h = ci >> 6, rem = ci & 63;
      int c = ((rem >> 4) << 1) | h;
      int r = rblk*16 + (rem & 15);
      gload_lds16(A + (m0 + r)*(long)K + k0 + c*16, As + seg*16);
    }
    #pragma unroll
    for (int it = 0; it < 4; ++it) {
      int seg  = tid + it*256;
      int rblk = seg >> 7, ci = seg & 127;
      int h = ci >> 6, rem = ci & 63;
      int c = ((rem >> 4) << 1) | h;
      int r = rblk*16 + (rem & 15);
      gload_lds16(Bt + (n0 + r)*(long)K + k0 + c*16, Bs + seg*16);
    }
    __syncthreads();

    // fragment: lane holds k = q*32..q*32+31 of its row; reads are
    // lane-contiguous (base + lane*16, +1024) -> conflict-free
    i32x8 a[FM], b[FN];
    #pragma unroll
    for (int i = 0; i < FM; ++i) {
      int rb = wm*4 + i;                     // (wm*HM + i*16) >> 4
      union { uint4 v[2]; i32x8 f; } u;
      const unsigned char* p = As + rb*2048 + lane*16;
      u.v[0] = *(const uint4*)p;
      u.v[1] = *(const uint4*)(p + 1024);
      a[i] = u.f;
    }
    #pragma unroll
    for (int j = 0; j < FN; ++j) {
      int rb = wn*4 + j;
      union { uint4 v[2]; i32x8 f; } u;
      const unsigned char* p = Bs + rb*2048 + lane*16;
      u.v[0] = *(const uint4*)p;
      u.v[1] = *(const uint4*)(p + 1024);
      b[j] = u.f;
    }
    #pragma unroll
    for (int i = 0; i < FM; ++i)
      #pragma unroll
      for (int j = 0; j < FN; ++j)
        acc[i][j] = __builtin_amdgcn_mfma_scale_f32_16x16x128_f8f6f4(
            a[i], b[j], acc[i][j], 0, 0, 0, E8M0_ACT, 0, E8M0_W);
    __syncthreads();
  }

  // epilogue: D col = lane&15, row = (lane>>4)*4 + r  [m89/m91 layout]
  if constexpr (ACT == 0) {
    // relu -> fp8 x2^6, repack via smem (row stride 144 breaks bank aliasing)
    #pragma unroll
    for (int j = 0; j < FN; ++j) {
      int cl = wn*HN + j*16 + l16;
      float bv = bias[n0 + cl];
      #pragma unroll
      for (int i = 0; i < FM; ++i) {
        #pragma unroll
        for (int r = 0; r < 4; ++r) {
          int rl = wm*HM + i*16 + q*4 + r;
          smem[rl*144 + cl] = f2fp8(fmaxf(acc[i][j][r] + bv, 0.f) * ACT_SCALE);
        }
      }
    }
    __syncthreads();
    unsigned char* C = (unsigned char*)Cptr;
    #pragma unroll
    for (int it = 0; it < 4; ++it) {
      int seg = tid + it*256;
      int row = seg >> 3;
      *(uint4*)(C + (m0 + row)*(long)ldC + n0 + (seg & 7)*16) =
          *(const uint4*)(smem + row*144 + (seg & 7)*16);
    }
  } else {
    float* C = (float*)Cptr;
    #pragma unroll
    for (int j = 0; j < FN; ++j) {
      long col = n0 + wn*HN + j*16 + l16;
      float bv = bias[col];
      #pragma unroll
      for (int i = 0; i < FM; ++i) {
        #pragma unroll
        for (int r = 0; r < 4; ++r) {
          long row = m0 + wm*HM + i*16 + q*4 + r;
          float v = acc[i][j][r] + bv;
          C[row*(long)ldC + col] = 1.f / (1.f + __expf(-v));
        }
      }
    }
  }
}

// ---- fused L2+L3+L4+L5: h1[4 rows] -> d1 (fp8 x2^6), all intermediates in LDS ----
// grid 2048 blocks x 256 threads (4 waves). Per-block weight traffic: W2C2 16KB,
// W3 40KB, W4 128KB, Wd1 128KB (each read once per block, L2-resident).
__global__ __launch_bounds__(256) void layer2345(
    const unsigned short* __restrict__ h1,
    const float* __restrict__ W2, const float* __restrict__ C2, const float* __restrict__ b2,
    const float* __restrict__ W3, const float* __restrict__ b3,
    const float* __restrict__ W4, const float* __restrict__ b4,
    const float* __restrict__ Wd1, const float* __restrict__ bd1,
    unsigned char* __restrict__ d1)
{
  __shared__ float h1s[4][200];
  __shared__ float h2s[4][10];
  __shared__ float h3s[4][1024];
  __shared__ float part[8][128];
  __shared__ float zs[4][32];
  const int t = threadIdx.x;
  const int w = t >> 6, l = t & 63;
  const long m0 = (long)blockIdx.x * 4;

  // load h1 rows (bf16 -> f32)
  for (int e = t; e < 4*196; e += 256) {
    int row = e / 196, col = e - row*196;
    h1s[row][col] = bf2f(h1[(m0 + row)*256 + col]);
  }
  __syncthreads();

  // L2: h2[r][10], wave w handles row w
  {
    float acc[10];
    #pragma unroll
    for (int n = 0; n < 10; ++n) acc[n] = 0.f;
    #pragma unroll
    for (int it = 0; it < 4; ++it) {
      int k = l + it*64;
      if (k < 196) {
        float a = h1s[w][k];
        #pragma unroll
        for (int n = 0; n < 10; ++n) acc[n] += a * W2[k*10 + n] * C2[k*10 + n];
      }
    }
    #pragma unroll
    for (int off = 32; off > 0; off >>= 1) {
      #pragma unroll
      for (int n = 0; n < 10; ++n) acc[n] += __shfl_down(acc[n], off, 64);
    }
    if (l < 10) h2s[w][l] = fmaxf(acc[l] + b2[l], 0.f);
  }
  __syncthreads();

  // L3: h3[r][1024]; wave w covers n = w*256 .. w*256+255, all 4 rows per thread
  #pragma unroll
  for (int jj = 0; jj < 4; ++jj) {
    int n = w*256 + jj*64 + l;
    float a0 = b3[n], a1 = a0, a2 = a0, a3 = a0;
    #pragma unroll
    for (int k = 0; k < 10; ++k) {
      float wv = W3[k*1024 + n];
      a0 += h2s[0][k]*wv; a1 += h2s[1][k]*wv;
      a2 += h2s[2][k]*wv; a3 += h2s[3][k]*wv;
    }
    h3s[0][n] = fmaxf(a0, 0.f); h3s[1][n] = fmaxf(a1, 0.f);
    h3s[2][n] = fmaxf(a2, 0.f); h3s[3][n] = fmaxf(a3, 0.f);
  }
  __syncthreads();

  // L4: z[r][32]; thread (kg = t>>5 in 0..7, n = t&31) covers k = kg*128..+127
  {
    int n = t & 31, kg = t >> 5;
    float a0 = 0.f, a1 = 0.f, a2 = 0.f, a3 = 0.f;
    for (int k = kg*128; k < kg*128 + 128; ++k) {
      float wv = W4[k*32 + n];
      a0 += h3s[0][k]*wv; a1 += h3s[1][k]*wv;
      a2 += h3s[2][k]*wv; a3 += h3s[3][k]*wv;
    }
    part[kg][0*32 + n] = a0; part[kg][1*32 + n] = a1;
    part[kg][2*32 + n] = a2; part[kg][3*32 + n] = a3;
  }
  __syncthreads();
  if (t < 128) {
    float s = 0.f;
    #pragma unroll
    for (int kg = 0; kg < 8; ++kg) s += part[kg][t];
    zs[t >> 5][t & 31] = fmaxf(s + b4[t & 31], 0.f);
  }
  __syncthreads();

  // L5: d1[r][1024] fp8 x2^6; wave w covers n = w*256..+255, 4 rows per thread
  #pragma unroll
  for (int jj = 0; jj < 4; ++jj) {
    int n = w*256 + jj*64 + l;
    float a0 = bd1[n], a1 = a0, a2 = a0, a3 = a0;
    #pragma unroll
    for (int k = 0; k < 32; ++k) {
      float wv = Wd1[k*1024 + n];
      a0 += zs[0][k]*wv; a1 += zs[1][k]*wv;
      a2 += zs[2][k]*wv; a3 += zs[3][k]*wv;
    }
    d1[(m0 + 0)*1024 + n] = f2fp8(fmaxf(a0, 0.f) * ACT_SCALE);
    d1[(m0 + 1)*1024 + n] = f2fp8(fmaxf(a1, 0.f) * ACT_SCALE);
    d1[(m0 + 2)*1024 + n] = f2fp8(fmaxf(a2, 0.f) * ACT_SCALE);
    d1[(m0 + 3)*1024 + n] = f2fp8(fmaxf(a3, 0.f) * ACT_SCALE);
  }
}

extern "C" void kernel_launch(void* const* d_in, const int* in_sizes, int n_in,
                              void* d_out, int out_size, void* d_ws, size_t ws_size,
                              hipStream_t stream)
{
  (void)in_sizes; (void)n_in; (void)out_size; (void)ws_size;
  const float* x   = (const float*)d_in[0];
  const float* C1  = (const float*)d_in[1];
  const float* W1  = (const float*)d_in[2];
  const float* b1  = (const float*)d_in[3];
  const float* C2  = (const float*)d_in[4];
  const float* W2  = (const float*)d_in[5];
  const float* b2  = (const float*)d_in[6];
  const float* W3  = (const float*)d_in[7];
  const float* b3  = (const float*)d_in[8];
  const float* W4  = (const float*)d_in[9];
  const float* b4  = (const float*)d_in[10];
  const float* Wd1 = (const float*)d_in[11];
  const float* bd1 = (const float*)d_in[12];
  const float* Wd2 = (const float*)d_in[13];
  const float* bd2 = (const float*)d_in[14];
  const float* Wd3 = (const float*)d_in[15];
  const float* bd3 = (const float*)d_in[16];
  float* out = (float*)d_out;

  char* ws = (char*)d_ws;
  size_t off = 0;
  auto alloc = [&](size_t bytes) -> void* {
    void* p = ws + off; off += (bytes + 255) & ~(size_t)255; return p;
  };
  unsigned char* Wt2 = (unsigned char*)alloc((size_t)2048*1024);   // Wd2^T fp8 x16
  unsigned char* Wt3 = (unsigned char*)alloc((size_t)4096*2048);   // Wd3^T fp8 x16
  unsigned*      pk  = (unsigned*)     alloc((size_t)196*21*4);    // packed sparse W1C1
  unsigned short* h1 = (unsigned short*)alloc((size_t)8192*256*2); // bf16
  unsigned char*  d1 = (unsigned char*) alloc((size_t)8192*1024);  // fp8 x2^6
  unsigned char*  d2 = (unsigned char*) alloc((size_t)8192*2048);  // fp8 x2^6

  // prep
  build_sparse<<<dim3(196), 256, 0, stream>>>(C1, W1, pk);
  transpose_fp8<<<dim3(1024/32, 2048/32), 256, 0, stream>>>(Wd2, Wt2, 1024, 2048);
  transpose_fp8<<<dim3(2048/32, 4096/32), 256, 0, stream>>>(Wd3, Wt3, 2048, 4096);

  // L1: h1 = relu(x @ (W1*C1) + b1) — sparse gather, x read once
  layer1_sparse<<<dim3(8192/2), 256, 0, stream>>>(x, pk, b1, h1);
  // L2..L5 fused
  layer2345<<<dim3(8192/4), 256, 0, stream>>>(h1, W2, C2, b2, W3, b3, W4, b4,
                                              Wd1, bd1, d1);
  // L6: d2 = relu(d1 @ Wd2 + bd2)  M=8192 N=2048 K=1024  (MX-fp8)
  gemm_fp8<0><<<dim3(8192/128, 2048/128), 256, 0, stream>>>(
      d1, Wt2, bd2, d2, 1024, 2048);
  // L7: out = sigmoid(d2 @ Wd3 + bd3)  M=8192 N=4096 K=2048  (MX-fp8)
  gemm_fp8<1><<<dim3(8192/128, 4096/128), 256, 0, stream>>>(
      d2, Wt3, bd3, out, 2048, 4096);
}

// Round 4
// 526.369 us; speedup vs baseline: 1.0658x; 1.0207x over previous
//
#include <hip/hip_runtime.h>
#include <hip/hip_fp8.h>
#include <cstdint>
#include <cstddef>

typedef __attribute__((ext_vector_type(4))) float f32x4;
typedef __attribute__((ext_vector_type(8))) int i32x8;

#define DEVINL __device__ __forceinline__

DEVINL unsigned short f2bf(float f){
  union { float f; unsigned u; } v; v.f = f;
  unsigned r = v.u + 0x7fffu + ((v.u >> 16) & 1u);  // RNE
  return (unsigned short)(r >> 16);
}
DEVINL float bf2f(unsigned short h){
  union { unsigned u; float f; } v; v.u = ((unsigned)h) << 16;
  return v.f;
}
DEVINL unsigned char f2fp8(float f){
  __hip_fp8_e4m3 t(f);           // OCP e4m3fn, saturating
  return (unsigned char)t.__x;
}
DEVINL void gload_lds16(const void* g, void* l){
  __builtin_amdgcn_global_load_lds((const __attribute__((address_space(1))) void*)g,
                                   (__attribute__((address_space(3))) void*)l, 16, 0, 0);
}

// scale constants: activations stored x2^6, weights x2^4; descale via e8m0 MFMA scales
#define ACT_SCALE 64.0f
#define W_SCALE   16.0f
#define E8M0_ACT  121   // 2^-6
#define E8M0_W    123   // 2^-4

// ---- weight prep: Wt[n][k] = fp8(W[k][n] * 16) ----
__global__ __launch_bounds__(256) void transpose_fp8(
    const float* __restrict__ W, unsigned char* __restrict__ Wt, int K, int N)
{
  __shared__ unsigned char tile[32][33];
  int k0 = blockIdx.x * 32, n0 = blockIdx.y * 32;
  int tx = threadIdx.x & 31, ty = threadIdx.x >> 5;
  #pragma unroll
  for (int i = 0; i < 4; ++i) {
    int k = k0 + ty + 8*i, n = n0 + tx;
    tile[ty + 8*i][tx] = f2fp8(W[(size_t)k*N + n] * W_SCALE);
  }
  __syncthreads();
  #pragma unroll
  for (int i = 0; i < 4; ++i) {
    int n = n0 + ty + 8*i, k = k0 + tx;
    Wt[(size_t)n*K + k] = tile[tx][ty + 8*i];
  }
}

// ---- L1 prep: compact knn mask column j -> 21 packed (idx<<16 | bf16(W1)) ----
// 4 waves, two-pass (count then place); slot order within column is irrelevant
// because the consumer only sums the terms.
__global__ __launch_bounds__(256) void build_sparse(
    const float* __restrict__ C1, const float* __restrict__ W1,
    unsigned* __restrict__ packed)
{
  const int j = blockIdx.x;            // 0..195
  const int w = threadIdx.x >> 6, l = threadIdx.x & 63;
  __shared__ int wcnt[4], wbase[4];
  // pass 1: per-wave nonzero count
  int cnt = 0;
  #pragma unroll 4
  for (int it = 0; it < 16; ++it) {
    int k = w*1024 + it*64 + l;
    float c = C1[(size_t)k*196 + j];
    unsigned long long m = __ballot(c != 0.f);
    cnt += (int)__popcll(m);
  }
  if (l == 0) wcnt[w] = cnt;
  __syncthreads();
  if (threadIdx.x < 21) packed[j*21 + threadIdx.x] = 0;  // safety vs poison
  if (threadIdx.x == 0) {
    int b = 0;
    #pragma unroll
    for (int i = 0; i < 4; ++i) { wbase[i] = b; b += wcnt[i]; }
  }
  __syncthreads();
  // pass 2: place (L2-hot reload)
  int base = wbase[w];
  #pragma unroll 4
  for (int it = 0; it < 16; ++it) {
    int k = w*1024 + it*64 + l;
    float c = C1[(size_t)k*196 + j];
    unsigned long long m = __ballot(c != 0.f);
    if (c != 0.f) {
      int pos = base + (int)__popcll(m & ((1ull << l) - 1ull));
      if (pos < 21)
        packed[j*21 + pos] = ((unsigned)k << 16)
                           | (unsigned)f2bf(W1[(size_t)k*196 + j] * c);
    }
    base += (int)__popcll(m);
  }
}

// ---- MX-fp8 MFMA GEMM: C = act(A[M,K] * Bt[N,K]^T + bias) ----
// EXACT round-0 structure (90us @ MfmaUtil 30%): LDS position of global 16B
// chunk g in row r: p = (5g + r) & 7 (multiplicative swizzle). Staging inverts
// at the GLOBAL source: g = (5d + 3r) & 7 -> full-row coalesced gload_lds.
// (Round-1/2 established: the read-conflict-free layout forces half-line
// staging under gload_lds -> net loss. This variant's 13% read-conflict tax
// is the cheaper side of the dichotomy.)
// ACT 0: relu -> fp8 x2^6 (LDS-repacked, stride 144, coalesced 16B stores);
// ACT 1: sigmoid -> fp32. Grid (M/128, N/128), 256 threads (2x2 waves).
template<int ACT>
__global__ __launch_bounds__(256) void gemm_fp8(
    const unsigned char* __restrict__ A, const unsigned char* __restrict__ Bt,
    const float* __restrict__ bias, void* __restrict__ Cptr, int K, int ldC)
{
  constexpr int BM = 128, BN = 128, BK = 128;
  constexpr int HM = 64, HN = 64, FM = 4, FN = 4;
  __shared__ __align__(16) unsigned char smem[32768];
  unsigned char* As = smem;
  unsigned char* Bs = smem + 16384;
  const int tid  = threadIdx.x;
  const int lane = tid & 63;
  const int w    = tid >> 6;
  const int wm = w & 1, wn = w >> 1;
  const int q = lane >> 4, l16 = lane & 15;
  const long m0 = (long)blockIdx.x * BM;
  const long n0 = (long)blockIdx.y * BN;

  f32x4 acc[FM][FN] = {};

  for (int k0 = 0; k0 < K; k0 += BK) {
    #pragma unroll
    for (int it = 0; it < 4; ++it) {
      int seg = tid + it*256;
      int row = seg >> 3;
      int g   = (5*(seg & 7) + 3*row) & 7;
      gload_lds16(A + (m0 + row)*(long)K + k0 + g*16, As + seg*16);
    }
    #pragma unroll
    for (int it = 0; it < 4; ++it) {
      int seg = tid + it*256;
      int row = seg >> 3;
      int g   = (5*(seg & 7) + 3*row) & 7;
      gload_lds16(Bt + (n0 + row)*(long)K + k0 + g*16, Bs + seg*16);
    }
    __syncthreads();

    // fragment: lane holds k = q*32..q*32+31 of row (verified by R3 absmax=0)
    i32x8 a[FM], b[FN];
    #pragma unroll
    for (int i = 0; i < FM; ++i) {
      int r = wm*HM + i*16 + l16;
      const uint4* p = (const uint4*)(As + r*BK);
      int c0 = (2*q + r) & 7;
      union { uint4 v[2]; i32x8 f; } u;
      u.v[0] = p[c0];
      u.v[1] = p[(c0 + 5) & 7];
      a[i] = u.f;
    }
    #pragma unroll
    for (int j = 0; j < FN; ++j) {
      int r = wn*HN + j*16 + l16;
      const uint4* p = (const uint4*)(Bs + r*BK);
      int c0 = (2*q + r) & 7;
      union { uint4 v[2]; i32x8 f; } u;
      u.v[0] = p[c0];
      u.v[1] = p[(c0 + 5) & 7];
      b[j] = u.f;
    }
    #pragma unroll
    for (int i = 0; i < FM; ++i)
      #pragma unroll
      for (int j = 0; j < FN; ++j)
        acc[i][j] = __builtin_amdgcn_mfma_scale_f32_16x16x128_f8f6f4(
            a[i], b[j], acc[i][j], 0, 0, 0, E8M0_ACT, 0, E8M0_W);
    __syncthreads();
  }

  // epilogue: D col = lane&15, row = (lane>>4)*4 + r  [m89/m91 layout]
  if constexpr (ACT == 0) {
    // relu -> fp8 x2^6, repack via smem (row stride 144 breaks bank aliasing)
    #pragma unroll
    for (int j = 0; j < FN; ++j) {
      int cl = wn*HN + j*16 + l16;
      float bv = bias[n0 + cl];
      #pragma unroll
      for (int i = 0; i < FM; ++i) {
        #pragma unroll
        for (int r = 0; r < 4; ++r) {
          int rl = wm*HM + i*16 + q*4 + r;
          smem[rl*144 + cl] = f2fp8(fmaxf(acc[i][j][r] + bv, 0.f) * ACT_SCALE);
        }
      }
    }
    __syncthreads();
    unsigned char* C = (unsigned char*)Cptr;
    #pragma unroll
    for (int it = 0; it < 4; ++it) {
      int seg = tid + it*256;
      int row = seg >> 3;
      *(uint4*)(C + (m0 + row)*(long)ldC + n0 + (seg & 7)*16) =
          *(const uint4*)(smem + row*144 + (seg & 7)*16);
    }
  } else {
    float* C = (float*)Cptr;
    #pragma unroll
    for (int j = 0; j < FN; ++j) {
      long col = n0 + wn*HN + j*16 + l16;
      float bv = bias[col];
      #pragma unroll
      for (int i = 0; i < FM; ++i) {
        #pragma unroll
        for (int r = 0; r < 4; ++r) {
          long row = m0 + wm*HM + i*16 + q*4 + r;
          float v = acc[i][j][r] + bv;
          C[row*(long)ldC + col] = 1.f / (1.f + __expf(-v));
        }
      }
    }
  }
}

// ---- fused L1+L2+L3+L4+L5: x[4 rows] -> d1 (fp8 x2^6), no h1 roundtrip ----
// grid 2048 blocks x 256 threads (4 waves). x staged in two 2-row halves
// through one 32KB LDS buffer (57KB total static LDS -> 2 blocks/CU).
// h1 values pass through bf16 rounding (bf2f(f2bf(.))) so numerics are
// bit-identical to the previous layer1_sparse -> layer2345 pipeline.
// Per-block weight traffic: W2C2 16KB, W3 40KB, W4 128KB, Wd1 128KB
// (each read once per block, L2-resident).
__global__ __launch_bounds__(256) void layer12345(
    const float* __restrict__ x, const unsigned* __restrict__ packed,
    const float* __restrict__ b1,
    const float* __restrict__ W2, const float* __restrict__ C2, const float* __restrict__ b2,
    const float* __restrict__ W3, const float* __restrict__ b3,
    const float* __restrict__ W4, const float* __restrict__ b4,
    const float* __restrict__ Wd1, const float* __restrict__ bd1,
    unsigned char* __restrict__ d1)
{
  __shared__ float xs[2*4096];       // 32KB, reused for each 2-row half
  __shared__ float h1s[4][200];
  __shared__ float h2s[4][10];
  __shared__ float h3s[4][1024];
  __shared__ float part[8][128];
  __shared__ float zs[4][32];
  const int t = threadIdx.x;
  const int w = t >> 6, l = t & 63;
  const long m0 = (long)blockIdx.x * 4;

  // L1: two halves of 2 rows each; x read exactly once, coalesced float4
  #pragma unroll
  for (int half = 0; half < 2; ++half) {
    const float4* src = (const float4*)(x + (m0 + half*2)*4096);
    #pragma unroll
    for (int i = 0; i < 8; ++i) ((float4*)xs)[t + i*256] = src[t + i*256];
    __syncthreads();
    for (int e = t; e < 2*196; e += 256) {
      int row = (e >= 196) ? 1 : 0;
      int col = e - row*196;
      const float* xr = xs + row*4096;
      float acc = b1[col];
      #pragma unroll
      for (int i = 0; i < 21; ++i) {
        unsigned p = packed[col*21 + i];          // L1-hot 16.5 KB table
        acc += xr[p >> 16] * bf2f((unsigned short)(p & 0xffffu));
      }
      // bf16 roundtrip preserved => identical numerics to split version
      h1s[half*2 + row][col] = bf2f(f2bf(fmaxf(acc, 0.f)));
    }
    __syncthreads();
  }

  // L2: h2[r][10], wave w handles row w
  {
    float acc[10];
    #pragma unroll
    for (int n = 0; n < 10; ++n) acc[n] = 0.f;
    #pragma unroll
    for (int it = 0; it < 4; ++it) {
      int k = l + it*64;
      if (k < 196) {
        float a = h1s[w][k];
        #pragma unroll
        for (int n = 0; n < 10; ++n) acc[n] += a * W2[k*10 + n] * C2[k*10 + n];
      }
    }
    #pragma unroll
    for (int off = 32; off > 0; off >>= 1) {
      #pragma unroll
      for (int n = 0; n < 10; ++n) acc[n] += __shfl_down(acc[n], off, 64);
    }
    if (l < 10) h2s[w][l] = fmaxf(acc[l] + b2[l], 0.f);
  }
  __syncthreads();

  // L3: h3[r][1024]; wave w covers n = w*256 .. w*256+255, all 4 rows per thread
  #pragma unroll
  for (int jj = 0; jj < 4; ++jj) {
    int n = w*256 + jj*64 + l;
    float a0 = b3[n], a1 = a0, a2 = a0, a3 = a0;
    #pragma unroll
    for (int k = 0; k < 10; ++k) {
      float wv = W3[k*1024 + n];
      a0 += h2s[0][k]*wv; a1 += h2s[1][k]*wv;
      a2 += h2s[2][k]*wv; a3 += h2s[3][k]*wv;
    }
    h3s[0][n] = fmaxf(a0, 0.f); h3s[1][n] = fmaxf(a1, 0.f);
    h3s[2][n] = fmaxf(a2, 0.f); h3s[3][n] = fmaxf(a3, 0.f);
  }
  __syncthreads();

  // L4: z[r][32]; thread (kg = t>>5 in 0..7, n = t&31) covers k = kg*128..+127
  {
    int n = t & 31, kg = t >> 5;
    float a0 = 0.f, a1 = 0.f, a2 = 0.f, a3 = 0.f;
    for (int k = kg*128; k < kg*128 + 128; ++k) {
      float wv = W4[k*32 + n];
      a0 += h3s[0][k]*wv; a1 += h3s[1][k]*wv;
      a2 += h3s[2][k]*wv; a3 += h3s[3][k]*wv;
    }
    part[kg][0*32 + n] = a0; part[kg][1*32 + n] = a1;
    part[kg][2*32 + n] = a2; part[kg][3*32 + n] = a3;
  }
  __syncthreads();
  if (t < 128) {
    float s = 0.f;
    #pragma unroll
    for (int kg = 0; kg < 8; ++kg) s += part[kg][t];
    zs[t >> 5][t & 31] = fmaxf(s + b4[t & 31], 0.f);
  }
  __syncthreads();

  // L5: d1[r][1024] fp8 x2^6; wave w covers n = w*256..+255, 4 rows per thread
  #pragma unroll
  for (int jj = 0; jj < 4; ++jj) {
    int n = w*256 + jj*64 + l;
    float a0 = bd1[n], a1 = a0, a2 = a0, a3 = a0;
    #pragma unroll
    for (int k = 0; k < 32; ++k) {
      float wv = Wd1[k*1024 + n];
      a0 += zs[0][k]*wv; a1 += zs[1][k]*wv;
      a2 += zs[2][k]*wv; a3 += zs[3][k]*wv;
    }
    d1[(m0 + 0)*1024 + n] = f2fp8(fmaxf(a0, 0.f) * ACT_SCALE);
    d1[(m0 + 1)*1024 + n] = f2fp8(fmaxf(a1, 0.f) * ACT_SCALE);
    d1[(m0 + 2)*1024 + n] = f2fp8(fmaxf(a2, 0.f) * ACT_SCALE);
    d1[(m0 + 3)*1024 + n] = f2fp8(fmaxf(a3, 0.f) * ACT_SCALE);
  }
}

extern "C" void kernel_launch(void* const* d_in, const int* in_sizes, int n_in,
                              void* d_out, int out_size, void* d_ws, size_t ws_size,
                              hipStream_t stream)
{
  (void)in_sizes; (void)n_in; (void)out_size; (void)ws_size;
  const float* x   = (const float*)d_in[0];
  const float* C1  = (const float*)d_in[1];
  const float* W1  = (const float*)d_in[2];
  const float* b1  = (const float*)d_in[3];
  const float* C2  = (const float*)d_in[4];
  const float* W2  = (const float*)d_in[5];
  const float* b2  = (const float*)d_in[6];
  const float* W3  = (const float*)d_in[7];
  const float* b3  = (const float*)d_in[8];
  const float* W4  = (const float*)d_in[9];
  const float* b4  = (const float*)d_in[10];
  const float* Wd1 = (const float*)d_in[11];
  const float* bd1 = (const float*)d_in[12];
  const float* Wd2 = (const float*)d_in[13];
  const float* bd2 = (const float*)d_in[14];
  const float* Wd3 = (const float*)d_in[15];
  const float* bd3 = (const float*)d_in[16];
  float* out = (float*)d_out;

  char* ws = (char*)d_ws;
  size_t off = 0;
  auto alloc = [&](size_t bytes) -> void* {
    void* p = ws + off; off += (bytes + 255) & ~(size_t)255; return p;
  };
  unsigned char* Wt2 = (unsigned char*)alloc((size_t)2048*1024);   // Wd2^T fp8 x16
  unsigned char* Wt3 = (unsigned char*)alloc((size_t)4096*2048);   // Wd3^T fp8 x16
  unsigned*      pk  = (unsigned*)     alloc((size_t)196*21*4);    // packed sparse W1C1
  unsigned char*  d1 = (unsigned char*) alloc((size_t)8192*1024);  // fp8 x2^6
  unsigned char*  d2 = (unsigned char*) alloc((size_t)8192*2048);  // fp8 x2^6

  // prep
  build_sparse<<<dim3(196), 256, 0, stream>>>(C1, W1, pk);
  transpose_fp8<<<dim3(1024/32, 2048/32), 256, 0, stream>>>(Wd2, Wt2, 1024, 2048);
  transpose_fp8<<<dim3(2048/32, 4096/32), 256, 0, stream>>>(Wd3, Wt3, 2048, 4096);

  // L1..L5 fused: x -> d1, no h1 roundtrip
  layer12345<<<dim3(8192/4), 256, 0, stream>>>(x, pk, b1, W2, C2, b2, W3, b3,
                                               W4, b4, Wd1, bd1, d1);
  // L6: d2 = relu(d1 @ Wd2 + bd2)  M=8192 N=2048 K=1024  (MX-fp8)
  gemm_fp8<0><<<dim3(8192/128, 2048/128), 256, 0, stream>>>(
      d1, Wt2, bd2, d2, 1024, 2048);
  // L7: out = sigmoid(d2 @ Wd3 + bd3)  M=8192 N=4096 K=2048  (MX-fp8)
  gemm_fp8<1><<<dim3(8192/128, 4096/128), 256, 0, stream>>>(
      d2, Wt3, bd3, out, 2048, 4096);
}

// Round 5
// 462.935 us; speedup vs baseline: 1.2118x; 1.1370x over previous
//
#include <hip/hip_runtime.h>
#include <hip/hip_fp8.h>
#include <cstdint>
#include <cstddef>

typedef __attribute__((ext_vector_type(4))) float f32x4;
typedef __attribute__((ext_vector_type(8))) int i32x8;

#define DEVINL __device__ __forceinline__

DEVINL unsigned short f2bf(float f){
  union { float f; unsigned u; } v; v.f = f;
  unsigned r = v.u + 0x7fffu + ((v.u >> 16) & 1u);  // RNE
  return (unsigned short)(r >> 16);
}
DEVINL float bf2f(unsigned short h){
  union { unsigned u; float f; } v; v.u = ((unsigned)h) << 16;
  return v.f;
}
DEVINL unsigned char f2fp8(float f){
  __hip_fp8_e4m3 t(f);           // OCP e4m3fn, saturating
  return (unsigned char)t.__x;
}
DEVINL void gload_lds16(const void* g, void* l){
  __builtin_amdgcn_global_load_lds((const __attribute__((address_space(1))) void*)g,
                                   (__attribute__((address_space(3))) void*)l, 16, 0, 0);
}

// scale constants: activations stored x2^6, weights x2^4; descale via e8m0 MFMA scales
#define ACT_SCALE 64.0f
#define W_SCALE   16.0f
#define E8M0_ACT  121   // 2^-6
#define E8M0_W    123   // 2^-4

// ---- weight prep: Wt[n][k] = fp8(W[k][n] * 16) ----
__global__ __launch_bounds__(256) void transpose_fp8(
    const float* __restrict__ W, unsigned char* __restrict__ Wt, int K, int N)
{
  __shared__ unsigned char tile[32][33];
  int k0 = blockIdx.x * 32, n0 = blockIdx.y * 32;
  int tx = threadIdx.x & 31, ty = threadIdx.x >> 5;
  #pragma unroll
  for (int i = 0; i < 4; ++i) {
    int k = k0 + ty + 8*i, n = n0 + tx;
    tile[ty + 8*i][tx] = f2fp8(W[(size_t)k*N + n] * W_SCALE);
  }
  __syncthreads();
  #pragma unroll
  for (int i = 0; i < 4; ++i) {
    int n = n0 + ty + 8*i, k = k0 + tx;
    Wt[(size_t)n*K + k] = tile[tx][ty + 8*i];
  }
}

// ---- L1 prep: compact knn mask column j -> 21 packed (idx<<16 | bf16(W1)) ----
// 4 waves, two-pass (count then place); slot order within column is irrelevant
// because the consumer only sums the terms.
__global__ __launch_bounds__(256) void build_sparse(
    const float* __restrict__ C1, const float* __restrict__ W1,
    unsigned* __restrict__ packed)
{
  const int j = blockIdx.x;            // 0..195
  const int w = threadIdx.x >> 6, l = threadIdx.x & 63;
  __shared__ int wcnt[4], wbase[4];
  // pass 1: per-wave nonzero count
  int cnt = 0;
  #pragma unroll 4
  for (int it = 0; it < 16; ++it) {
    int k = w*1024 + it*64 + l;
    float c = C1[(size_t)k*196 + j];
    unsigned long long m = __ballot(c != 0.f);
    cnt += (int)__popcll(m);
  }
  if (l == 0) wcnt[w] = cnt;
  __syncthreads();
  if (threadIdx.x < 21) packed[j*21 + threadIdx.x] = 0;  // safety vs poison
  if (threadIdx.x == 0) {
    int b = 0;
    #pragma unroll
    for (int i = 0; i < 4; ++i) { wbase[i] = b; b += wcnt[i]; }
  }
  __syncthreads();
  // pass 2: place (L2-hot reload)
  int base = wbase[w];
  #pragma unroll 4
  for (int it = 0; it < 16; ++it) {
    int k = w*1024 + it*64 + l;
    float c = C1[(size_t)k*196 + j];
    unsigned long long m = __ballot(c != 0.f);
    if (c != 0.f) {
      int pos = base + (int)__popcll(m & ((1ull << l) - 1ull));
      if (pos < 21)
        packed[j*21 + pos] = ((unsigned)k << 16)
                           | (unsigned)f2bf(W1[(size_t)k*196 + j] * c);
    }
    base += (int)__popcll(m);
  }
}

// ---- L1: h1 = relu(x @ sparse(W1*C1) + b1), 2 rows/block, x read exactly once ----
// Round-5 change (one variable): stage x via global_load_lds (width 16) instead
// of float4 VGPR roundtrip. Dest is wave-linear (uniform base + lane*16) and
// source contiguous, so this is a drop-in; __syncthreads() drains vmcnt before
// any xs read (compiler emits the full waitcnt before s_barrier).
__global__ __launch_bounds__(256) void layer1_sparse(
    const float* __restrict__ x, const unsigned* __restrict__ packed,
    const float* __restrict__ b1, unsigned short* __restrict__ h1)
{
  __shared__ __align__(16) float xs[2*4096];
  const int t = threadIdx.x;
  const long m0 = (long)blockIdx.x * 2;
  const char* src = (const char*)(x + m0*4096);
  #pragma unroll
  for (int i = 0; i < 8; ++i) {
    int seg = t + i*256;                       // 0..2047, 16B each
    gload_lds16(src + (size_t)seg*16, (char*)xs + (size_t)seg*16);
  }
  __syncthreads();
  for (int e = t; e < 2*196; e += 256) {
    int row = (e >= 196) ? 1 : 0;
    int col = e - row*196;
    const float* xr = xs + row*4096;
    float acc = b1[col];
    #pragma unroll
    for (int i = 0; i < 21; ++i) {
      unsigned p = packed[col*21 + i];          // L1-hot 16.5 KB table
      acc += xr[p >> 16] * bf2f((unsigned short)(p & 0xffffu));
    }
    h1[(m0 + row)*256 + col] = f2bf(fmaxf(acc, 0.f));
  }
}

// ---- MX-fp8 MFMA GEMM: C = act(A[M,K] * Bt[N,K]^T + bias) ----
// EXACT round-0 structure (90us @ MfmaUtil 30%): LDS position of global 16B
// chunk g in row r: p = (5g + r) & 7 (multiplicative swizzle). Staging inverts
// at the GLOBAL source: g = (5d + 3r) & 7 -> full-row coalesced gload_lds.
// (Rounds 1/2 established: the read-conflict-free layout forces half-line
// staging under gload_lds -> net loss; the 8-phase 256^2 schedule at 1 block/CU
// stalls on load latency -> bigger loss. This variant's 13% read-conflict tax
// is the measured optimum of the explored family.)
// ACT 0: relu -> fp8 x2^6 (LDS-repacked, stride 144, coalesced 16B stores);
// ACT 1: sigmoid -> fp32. Grid (M/128, N/128), 256 threads (2x2 waves).
template<int ACT>
__global__ __launch_bounds__(256) void gemm_fp8(
    const unsigned char* __restrict__ A, const unsigned char* __restrict__ Bt,
    const float* __restrict__ bias, void* __restrict__ Cptr, int K, int ldC)
{
  constexpr int BM = 128, BN = 128, BK = 128;
  constexpr int HM = 64, HN = 64, FM = 4, FN = 4;
  __shared__ __align__(16) unsigned char smem[32768];
  unsigned char* As = smem;
  unsigned char* Bs = smem + 16384;
  const int tid  = threadIdx.x;
  const int lane = tid & 63;
  const int w    = tid >> 6;
  const int wm = w & 1, wn = w >> 1;
  const int q = lane >> 4, l16 = lane & 15;
  const long m0 = (long)blockIdx.x * BM;
  const long n0 = (long)blockIdx.y * BN;

  f32x4 acc[FM][FN] = {};

  for (int k0 = 0; k0 < K; k0 += BK) {
    #pragma unroll
    for (int it = 0; it < 4; ++it) {
      int seg = tid + it*256;
      int row = seg >> 3;
      int g   = (5*(seg & 7) + 3*row) & 7;
      gload_lds16(A + (m0 + row)*(long)K + k0 + g*16, As + seg*16);
    }
    #pragma unroll
    for (int it = 0; it < 4; ++it) {
      int seg = tid + it*256;
      int row = seg >> 3;
      int g   = (5*(seg & 7) + 3*row) & 7;
      gload_lds16(Bt + (n0 + row)*(long)K + k0 + g*16, Bs + seg*16);
    }
    __syncthreads();

    // fragment: lane holds k = q*32..q*32+31 of row (verified absmax=0)
    i32x8 a[FM], b[FN];
    #pragma unroll
    for (int i = 0; i < FM; ++i) {
      int r = wm*HM + i*16 + l16;
      const uint4* p = (const uint4*)(As + r*BK);
      int c0 = (2*q + r) & 7;
      union { uint4 v[2]; i32x8 f; } u;
      u.v[0] = p[c0];
      u.v[1] = p[(c0 + 5) & 7];
      a[i] = u.f;
    }
    #pragma unroll
    for (int j = 0; j < FN; ++j) {
      int r = wn*HN + j*16 + l16;
      const uint4* p = (const uint4*)(Bs + r*BK);
      int c0 = (2*q + r) & 7;
      union { uint4 v[2]; i32x8 f; } u;
      u.v[0] = p[c0];
      u.v[1] = p[(c0 + 5) & 7];
      b[j] = u.f;
    }
    #pragma unroll
    for (int i = 0; i < FM; ++i)
      #pragma unroll
      for (int j = 0; j < FN; ++j)
        acc[i][j] = __builtin_amdgcn_mfma_scale_f32_16x16x128_f8f6f4(
            a[i], b[j], acc[i][j], 0, 0, 0, E8M0_ACT, 0, E8M0_W);
    __syncthreads();
  }

  // epilogue: D col = lane&15, row = (lane>>4)*4 + r  [m89/m91 layout]
  if constexpr (ACT == 0) {
    // relu -> fp8 x2^6, repack via smem (row stride 144 breaks bank aliasing)
    #pragma unroll
    for (int j = 0; j < FN; ++j) {
      int cl = wn*HN + j*16 + l16;
      float bv = bias[n0 + cl];
      #pragma unroll
      for (int i = 0; i < FM; ++i) {
        #pragma unroll
        for (int r = 0; r < 4; ++r) {
          int rl = wm*HM + i*16 + q*4 + r;
          smem[rl*144 + cl] = f2fp8(fmaxf(acc[i][j][r] + bv, 0.f) * ACT_SCALE);
        }
      }
    }
    __syncthreads();
    unsigned char* C = (unsigned char*)Cptr;
    #pragma unroll
    for (int it = 0; it < 4; ++it) {
      int seg = tid + it*256;
      int row = seg >> 3;
      *(uint4*)(C + (m0 + row)*(long)ldC + n0 + (seg & 7)*16) =
          *(const uint4*)(smem + row*144 + (seg & 7)*16);
    }
  } else {
    float* C = (float*)Cptr;
    #pragma unroll
    for (int j = 0; j < FN; ++j) {
      long col = n0 + wn*HN + j*16 + l16;
      float bv = bias[col];
      #pragma unroll
      for (int i = 0; i < FM; ++i) {
        #pragma unroll
        for (int r = 0; r < 4; ++r) {
          long row = m0 + wm*HM + i*16 + q*4 + r;
          float v = acc[i][j][r] + bv;
          C[row*(long)ldC + col] = 1.f / (1.f + __expf(-v));
        }
      }
    }
  }
}

// ---- fused L2+L3+L4+L5: h1[4 rows] -> d1 (fp8 x2^6), all intermediates in LDS ----
// grid 2048 blocks x 256 threads (4 waves), 24KB LDS -> 6 blocks/CU.
// Per-block weight traffic: W2C2 16KB, W3 40KB, W4 128KB, Wd1 128KB
// (each read once per block, L2-resident).
__global__ __launch_bounds__(256) void layer2345(
    const unsigned short* __restrict__ h1,
    const float* __restrict__ W2, const float* __restrict__ C2, const float* __restrict__ b2,
    const float* __restrict__ W3, const float* __restrict__ b3,
    const float* __restrict__ W4, const float* __restrict__ b4,
    const float* __restrict__ Wd1, const float* __restrict__ bd1,
    unsigned char* __restrict__ d1)
{
  __shared__ float h1s[4][200];
  __shared__ float h2s[4][10];
  __shared__ float h3s[4][1024];
  __shared__ float part[8][128];
  __shared__ float zs[4][32];
  const int t = threadIdx.x;
  const int w = t >> 6, l = t & 63;
  const long m0 = (long)blockIdx.x * 4;

  // load h1 rows (bf16 -> f32)
  for (int e = t; e < 4*196; e += 256) {
    int row = e / 196, col = e - row*196;
    h1s[row][col] = bf2f(h1[(m0 + row)*256 + col]);
  }
  __syncthreads();

  // L2: h2[r][10], wave w handles row w
  {
    float acc[10];
    #pragma unroll
    for (int n = 0; n < 10; ++n) acc[n] = 0.f;
    #pragma unroll
    for (int it = 0; it < 4; ++it) {
      int k = l + it*64;
      if (k < 196) {
        float a = h1s[w][k];
        #pragma unroll
        for (int n = 0; n < 10; ++n) acc[n] += a * W2[k*10 + n] * C2[k*10 + n];
      }
    }
    #pragma unroll
    for (int off = 32; off > 0; off >>= 1) {
      #pragma unroll
      for (int n = 0; n < 10; ++n) acc[n] += __shfl_down(acc[n], off, 64);
    }
    if (l < 10) h2s[w][l] = fmaxf(acc[l] + b2[l], 0.f);
  }
  __syncthreads();

  // L3: h3[r][1024]; wave w covers n = w*256 .. w*256+255, all 4 rows per thread
  #pragma unroll
  for (int jj = 0; jj < 4; ++jj) {
    int n = w*256 + jj*64 + l;
    float a0 = b3[n], a1 = a0, a2 = a0, a3 = a0;
    #pragma unroll
    for (int k = 0; k < 10; ++k) {
      float wv = W3[k*1024 + n];
      a0 += h2s[0][k]*wv; a1 += h2s[1][k]*wv;
      a2 += h2s[2][k]*wv; a3 += h2s[3][k]*wv;
    }
    h3s[0][n] = fmaxf(a0, 0.f); h3s[1][n] = fmaxf(a1, 0.f);
    h3s[2][n] = fmaxf(a2, 0.f); h3s[3][n] = fmaxf(a3, 0.f);
  }
  __syncthreads();

  // L4: z[r][32]; thread (kg = t>>5 in 0..7, n = t&31) covers k = kg*128..+127
  {
    int n = t & 31, kg = t >> 5;
    float a0 = 0.f, a1 = 0.f, a2 = 0.f, a3 = 0.f;
    for (int k = kg*128; k < kg*128 + 128; ++k) {
      float wv = W4[k*32 + n];
      a0 += h3s[0][k]*wv; a1 += h3s[1][k]*wv;
      a2 += h3s[2][k]*wv; a3 += h3s[3][k]*wv;
    }
    part[kg][0*32 + n] = a0; part[kg][1*32 + n] = a1;
    part[kg][2*32 + n] = a2; part[kg][3*32 + n] = a3;
  }
  __syncthreads();
  if (t < 128) {
    float s = 0.f;
    #pragma unroll
    for (int kg = 0; kg < 8; ++kg) s += part[kg][t];
    zs[t >> 5][t & 31] = fmaxf(s + b4[t & 31], 0.f);
  }
  __syncthreads();

  // L5: d1[r][1024] fp8 x2^6; wave w covers n = w*256..+255, 4 rows per thread
  #pragma unroll
  for (int jj = 0; jj < 4; ++jj) {
    int n = w*256 + jj*64 + l;
    float a0 = bd1[n], a1 = a0, a2 = a0, a3 = a0;
    #pragma unroll
    for (int k = 0; k < 32; ++k) {
      float wv = Wd1[k*1024 + n];
      a0 += zs[0][k]*wv; a1 += zs[1][k]*wv;
      a2 += zs[2][k]*wv; a3 += zs[3][k]*wv;
    }
    d1[(m0 + 0)*1024 + n] = f2fp8(fmaxf(a0, 0.f) * ACT_SCALE);
    d1[(m0 + 1)*1024 + n] = f2fp8(fmaxf(a1, 0.f) * ACT_SCALE);
    d1[(m0 + 2)*1024 + n] = f2fp8(fmaxf(a2, 0.f) * ACT_SCALE);
    d1[(m0 + 3)*1024 + n] = f2fp8(fmaxf(a3, 0.f) * ACT_SCALE);
  }
}

extern "C" void kernel_launch(void* const* d_in, const int* in_sizes, int n_in,
                              void* d_out, int out_size, void* d_ws, size_t ws_size,
                              hipStream_t stream)
{
  (void)in_sizes; (void)n_in; (void)out_size; (void)ws_size;
  const float* x   = (const float*)d_in[0];
  const float* C1  = (const float*)d_in[1];
  const float* W1  = (const float*)d_in[2];
  const float* b1  = (const float*)d_in[3];
  const float* C2  = (const float*)d_in[4];
  const float* W2  = (const float*)d_in[5];
  const float* b2  = (const float*)d_in[6];
  const float* W3  = (const float*)d_in[7];
  const float* b3  = (const float*)d_in[8];
  const float* W4  = (const float*)d_in[9];
  const float* b4  = (const float*)d_in[10];
  const float* Wd1 = (const float*)d_in[11];
  const float* bd1 = (const float*)d_in[12];
  const float* Wd2 = (const float*)d_in[13];
  const float* bd2 = (const float*)d_in[14];
  const float* Wd3 = (const float*)d_in[15];
  const float* bd3 = (const float*)d_in[16];
  float* out = (float*)d_out;

  char* ws = (char*)d_ws;
  size_t off = 0;
  auto alloc = [&](size_t bytes) -> void* {
    void* p = ws + off; off += (bytes + 255) & ~(size_t)255; return p;
  };
  unsigned char* Wt2 = (unsigned char*)alloc((size_t)2048*1024);   // Wd2^T fp8 x16
  unsigned char* Wt3 = (unsigned char*)alloc((size_t)4096*2048);   // Wd3^T fp8 x16
  unsigned*      pk  = (unsigned*)     alloc((size_t)196*21*4);    // packed sparse W1C1
  unsigned short* h1 = (unsigned short*)alloc((size_t)8192*256*2); // bf16
  unsigned char*  d1 = (unsigned char*) alloc((size_t)8192*1024);  // fp8 x2^6
  unsigned char*  d2 = (unsigned char*) alloc((size_t)8192*2048);  // fp8 x2^6

  // prep
  build_sparse<<<dim3(196), 256, 0, stream>>>(C1, W1, pk);
  transpose_fp8<<<dim3(1024/32, 2048/32), 256, 0, stream>>>(Wd2, Wt2, 1024, 2048);
  transpose_fp8<<<dim3(2048/32, 4096/32), 256, 0, stream>>>(Wd3, Wt3, 2048, 4096);

  // L1: h1 = relu(x @ (W1*C1) + b1) — sparse gather, x read once
  layer1_sparse<<<dim3(8192/2), 256, 0, stream>>>(x, pk, b1, h1);
  // L2..L5 fused
  layer2345<<<dim3(8192/4), 256, 0, stream>>>(h1, W2, C2, b2, W3, b3, W4, b4,
                                              Wd1, bd1, d1);
  // L6: d2 = relu(d1 @ Wd2 + bd2)  M=8192 N=2048 K=1024  (MX-fp8)
  gemm_fp8<0><<<dim3(8192/128, 2048/128), 256, 0, stream>>>(
      d1, Wt2, bd2, d2, 1024, 2048);
  // L7: out = sigmoid(d2 @ Wd3 + bd3)  M=8192 N=4096 K=2048  (MX-fp8)
  gemm_fp8<1><<<dim3(8192/128, 4096/128), 256, 0, stream>>>(
      d2, Wt3, bd3, out, 2048, 4096);
}

// Round 6
// 458.654 us; speedup vs baseline: 1.2231x; 1.0093x over previous
//
#include <hip/hip_runtime.h>
#include <hip/hip_fp8.h>
#include <cstdint>
#include <cstddef>

typedef __attribute__((ext_vector_type(4))) float f32x4;
typedef __attribute__((ext_vector_type(8))) int i32x8;

#define DEVINL __device__ __forceinline__

DEVINL unsigned short f2bf(float f){
  union { float f; unsigned u; } v; v.f = f;
  unsigned r = v.u + 0x7fffu + ((v.u >> 16) & 1u);  // RNE
  return (unsigned short)(r >> 16);
}
DEVINL float bf2f(unsigned short h){
  union { unsigned u; float f; } v; v.u = ((unsigned)h) << 16;
  return v.f;
}
DEVINL unsigned char f2fp8(float f){
  __hip_fp8_e4m3 t(f);           // OCP e4m3fn, saturating
  return (unsigned char)t.__x;
}
DEVINL void gload_lds16(const void* g, void* l){
  __builtin_amdgcn_global_load_lds((const __attribute__((address_space(1))) void*)g,
                                   (__attribute__((address_space(3))) void*)l, 16, 0, 0);
}

// scale constants: activations stored x2^6, weights x2^4; descale via e8m0 MFMA scales
#define ACT_SCALE 64.0f
#define W_SCALE   16.0f
#define E8M0_ACT  121   // 2^-6
#define E8M0_W    123   // 2^-4

// ---- weight prep: Wt[n][k] = fp8(W[k][n] * 16) ----
__global__ __launch_bounds__(256) void transpose_fp8(
    const float* __restrict__ W, unsigned char* __restrict__ Wt, int K, int N)
{
  __shared__ unsigned char tile[32][33];
  int k0 = blockIdx.x * 32, n0 = blockIdx.y * 32;
  int tx = threadIdx.x & 31, ty = threadIdx.x >> 5;
  #pragma unroll
  for (int i = 0; i < 4; ++i) {
    int k = k0 + ty + 8*i, n = n0 + tx;
    tile[ty + 8*i][tx] = f2fp8(W[(size_t)k*N + n] * W_SCALE);
  }
  __syncthreads();
  #pragma unroll
  for (int i = 0; i < 4; ++i) {
    int n = n0 + ty + 8*i, k = k0 + tx;
    Wt[(size_t)n*K + k] = tile[tx][ty + 8*i];
  }
}

// ---- L1 prep: compact knn mask column j -> 21 packed (idx<<16 | bf16(W1)) ----
// 4 waves, two-pass (count then place); slot order within column is irrelevant
// because the consumer only sums the terms.
__global__ __launch_bounds__(256) void build_sparse(
    const float* __restrict__ C1, const float* __restrict__ W1,
    unsigned* __restrict__ packed)
{
  const int j = blockIdx.x;            // 0..195
  const int w = threadIdx.x >> 6, l = threadIdx.x & 63;
  __shared__ int wcnt[4], wbase[4];
  // pass 1: per-wave nonzero count
  int cnt = 0;
  #pragma unroll 4
  for (int it = 0; it < 16; ++it) {
    int k = w*1024 + it*64 + l;
    float c = C1[(size_t)k*196 + j];
    unsigned long long m = __ballot(c != 0.f);
    cnt += (int)__popcll(m);
  }
  if (l == 0) wcnt[w] = cnt;
  __syncthreads();
  if (threadIdx.x < 21) packed[j*21 + threadIdx.x] = 0;  // safety vs poison
  if (threadIdx.x == 0) {
    int b = 0;
    #pragma unroll
    for (int i = 0; i < 4; ++i) { wbase[i] = b; b += wcnt[i]; }
  }
  __syncthreads();
  // pass 2: place (L2-hot reload)
  int base = wbase[w];
  #pragma unroll 4
  for (int it = 0; it < 16; ++it) {
    int k = w*1024 + it*64 + l;
    float c = C1[(size_t)k*196 + j];
    unsigned long long m = __ballot(c != 0.f);
    if (c != 0.f) {
      int pos = base + (int)__popcll(m & ((1ull << l) - 1ull));
      if (pos < 21)
        packed[j*21 + pos] = ((unsigned)k << 16)
                           | (unsigned)f2bf(W1[(size_t)k*196 + j] * c);
    }
    base += (int)__popcll(m);
  }
}

// ---- L1: h1 = relu(x @ sparse(W1*C1) + b1), 2 rows/block, x read exactly once ----
// x staged via global_load_lds width-16 (round-5 measured-good state).
__global__ __launch_bounds__(256) void layer1_sparse(
    const float* __restrict__ x, const unsigned* __restrict__ packed,
    const float* __restrict__ b1, unsigned short* __restrict__ h1)
{
  __shared__ __align__(16) float xs[2*4096];
  const int t = threadIdx.x;
  const long m0 = (long)blockIdx.x * 2;
  const char* src = (const char*)(x + m0*4096);
  #pragma unroll
  for (int i = 0; i < 8; ++i) {
    int seg = t + i*256;                       // 0..2047, 16B each
    gload_lds16(src + (size_t)seg*16, (char*)xs + (size_t)seg*16);
  }
  __syncthreads();
  for (int e = t; e < 2*196; e += 256) {
    int row = (e >= 196) ? 1 : 0;
    int col = e - row*196;
    const float* xr = xs + row*4096;
    float acc = b1[col];
    #pragma unroll
    for (int i = 0; i < 21; ++i) {
      unsigned p = packed[col*21 + i];          // L1-hot 16.5 KB table
      acc += xr[p >> 16] * bf2f((unsigned short)(p & 0xffffu));
    }
    h1[(m0 + row)*256 + col] = f2bf(fmaxf(acc, 0.f));
  }
}

// ---- MX-fp8 MFMA GEMM: C = act(A[M,K] * Bt[N,K]^T + bias) ----
// Round-6 change (one variable): block tile 128x256, per-wave tile 128x64
// (FM=8, FN=4, waves 1x4). Rationale: round-5 counters show the kernel is
// LDS-read-throughput-bound (MFMA floor 29us of 108; LDS ~55us incl. the
// irreducible 1.5x conflict tax). LDS-read bytes/FLOP ~ (WM+WN)/(2*WM*WN):
// 64x64 wave tile -> 1/64, 128x64 -> 1/85 => 25% fewer fragment reads.
// Same (5g+r)&7 chunk swizzle, same staging (full-line gload_lds), same
// fragment formulas — only row/col ranges change. 48KB LDS + ~240 VGPR ->
// 2 blocks/CU (8 waves), loose 2-phase overlap (NOT round-1's lockstep).
// ACT 0: relu -> fp8 x2^6 (LDS-repacked, stride 272, coalesced 16B stores);
// ACT 1: sigmoid -> fp32. Grid (M/128, N/256), 256 threads.
template<int ACT>
__global__ __launch_bounds__(256, 2) void gemm_fp8(
    const unsigned char* __restrict__ A, const unsigned char* __restrict__ Bt,
    const float* __restrict__ bias, void* __restrict__ Cptr, int K, int ldC)
{
  constexpr int BM = 128, BN = 256, BK = 128;
  constexpr int FM = 8, FN = 4;
  __shared__ __align__(16) unsigned char smem[49152];
  unsigned char* As = smem;             // 16KB: 128 rows x 128B
  unsigned char* Bs = smem + 16384;     // 32KB: 256 rows x 128B
  const int tid  = threadIdx.x;
  const int lane = tid & 63;
  const int w    = tid >> 6;            // wave n-slot 0..3 (wm is trivial)
  const int q = lane >> 4, l16 = lane & 15;
  const long m0 = (long)blockIdx.x * BM;
  const long n0 = (long)blockIdx.y * BN;

  f32x4 acc[FM][FN] = {};

  for (int k0 = 0; k0 < K; k0 += BK) {
    // stage A: 1024 segs (128 rows x 8 chunks), 4 rounds, full-line coalesced
    #pragma unroll
    for (int it = 0; it < 4; ++it) {
      int seg = tid + it*256;
      int row = seg >> 3;
      int g   = (5*(seg & 7) + 3*row) & 7;
      gload_lds16(A + (m0 + row)*(long)K + k0 + g*16, As + seg*16);
    }
    // stage B: 2048 segs (256 rows x 8 chunks), 8 rounds
    #pragma unroll
    for (int it = 0; it < 8; ++it) {
      int seg = tid + it*256;
      int row = seg >> 3;
      int g   = (5*(seg & 7) + 3*row) & 7;
      gload_lds16(Bt + (n0 + row)*(long)K + k0 + g*16, Bs + seg*16);
    }
    __syncthreads();

    // fragment: lane holds k = q*32..q*32+31 of its row (slots c0, c0+5)
    i32x8 b[FN];
    #pragma unroll
    for (int j = 0; j < FN; ++j) {
      int r = w*64 + j*16 + l16;
      const uint4* p = (const uint4*)(Bs + r*BK);
      int c0 = (2*q + r) & 7;
      union { uint4 v[2]; i32x8 f; } u;
      u.v[0] = p[c0];
      u.v[1] = p[(c0 + 5) & 7];
      b[j] = u.f;
    }
    #pragma unroll
    for (int i = 0; i < FM; ++i) {
      int r = i*16 + l16;
      const uint4* p = (const uint4*)(As + r*BK);
      int c0 = (2*q + r) & 7;
      union { uint4 v[2]; i32x8 f; } u;
      u.v[0] = p[c0];
      u.v[1] = p[(c0 + 5) & 7];
      i32x8 a = u.f;
      #pragma unroll
      for (int j = 0; j < FN; ++j)
        acc[i][j] = __builtin_amdgcn_mfma_scale_f32_16x16x128_f8f6f4(
            a, b[j], acc[i][j], 0, 0, 0, E8M0_ACT, 0, E8M0_W);
    }
    __syncthreads();
  }

  // epilogue: D col = lane&15, row = (lane>>4)*4 + r  [m89/m91 layout]
  if constexpr (ACT == 0) {
    // relu -> fp8 x2^6, repack via smem (row stride 272 = 17x16: aligned,
    // breaks 256-alias). 128 rows x 256 cols = 34.8KB <= 48KB buffer.
    #pragma unroll
    for (int j = 0; j < FN; ++j) {
      int cl = w*64 + j*16 + l16;
      float bv = bias[n0 + cl];
      #pragma unroll
      for (int i = 0; i < FM; ++i) {
        #pragma unroll
        for (int r = 0; r < 4; ++r) {
          int rl = i*16 + q*4 + r;
          smem[rl*272 + cl] = f2fp8(fmaxf(acc[i][j][r] + bv, 0.f) * ACT_SCALE);
        }
      }
    }
    __syncthreads();
    unsigned char* C = (unsigned char*)Cptr;
    #pragma unroll
    for (int it = 0; it < 8; ++it) {
      int seg = tid + it*256;           // 2048 segs: 128 rows x 16 chunks
      int row = seg >> 4, ch = seg & 15;
      *(uint4*)(C + (m0 + row)*(long)ldC + n0 + ch*16) =
          *(const uint4*)(smem + row*272 + ch*16);
    }
  } else {
    float* C = (float*)Cptr;
    #pragma unroll
    for (int j = 0; j < FN; ++j) {
      long col = n0 + w*64 + j*16 + l16;
      float bv = bias[col];
      #pragma unroll
      for (int i = 0; i < FM; ++i) {
        #pragma unroll
        for (int r = 0; r < 4; ++r) {
          long row = m0 + i*16 + q*4 + r;
          float v = acc[i][j][r] + bv;
          C[row*(long)ldC + col] = 1.f / (1.f + __expf(-v));
        }
      }
    }
  }
}

// ---- fused L2+L3+L4+L5: h1[4 rows] -> d1 (fp8 x2^6), all intermediates in LDS ----
// grid 2048 blocks x 256 threads (4 waves), 24KB LDS -> 6 blocks/CU.
// Per-block weight traffic: W2C2 16KB, W3 40KB, W4 128KB, Wd1 128KB
// (each read once per block, L2-resident).
__global__ __launch_bounds__(256) void layer2345(
    const unsigned short* __restrict__ h1,
    const float* __restrict__ W2, const float* __restrict__ C2, const float* __restrict__ b2,
    const float* __restrict__ W3, const float* __restrict__ b3,
    const float* __restrict__ W4, const float* __restrict__ b4,
    const float* __restrict__ Wd1, const float* __restrict__ bd1,
    unsigned char* __restrict__ d1)
{
  __shared__ float h1s[4][200];
  __shared__ float h2s[4][10];
  __shared__ float h3s[4][1024];
  __shared__ float part[8][128];
  __shared__ float zs[4][32];
  const int t = threadIdx.x;
  const int w = t >> 6, l = t & 63;
  const long m0 = (long)blockIdx.x * 4;

  // load h1 rows (bf16 -> f32)
  for (int e = t; e < 4*196; e += 256) {
    int row = e / 196, col = e - row*196;
    h1s[row][col] = bf2f(h1[(m0 + row)*256 + col]);
  }
  __syncthreads();

  // L2: h2[r][10], wave w handles row w
  {
    float acc[10];
    #pragma unroll
    for (int n = 0; n < 10; ++n) acc[n] = 0.f;
    #pragma unroll
    for (int it = 0; it < 4; ++it) {
      int k = l + it*64;
      if (k < 196) {
        float a = h1s[w][k];
        #pragma unroll
        for (int n = 0; n < 10; ++n) acc[n] += a * W2[k*10 + n] * C2[k*10 + n];
      }
    }
    #pragma unroll
    for (int off = 32; off > 0; off >>= 1) {
      #pragma unroll
      for (int n = 0; n < 10; ++n) acc[n] += __shfl_down(acc[n], off, 64);
    }
    if (l < 10) h2s[w][l] = fmaxf(acc[l] + b2[l], 0.f);
  }
  __syncthreads();

  // L3: h3[r][1024]; wave w covers n = w*256 .. w*256+255, all 4 rows per thread
  #pragma unroll
  for (int jj = 0; jj < 4; ++jj) {
    int n = w*256 + jj*64 + l;
    float a0 = b3[n], a1 = a0, a2 = a0, a3 = a0;
    #pragma unroll
    for (int k = 0; k < 10; ++k) {
      float wv = W3[k*1024 + n];
      a0 += h2s[0][k]*wv; a1 += h2s[1][k]*wv;
      a2 += h2s[2][k]*wv; a3 += h2s[3][k]*wv;
    }
    h3s[0][n] = fmaxf(a0, 0.f); h3s[1][n] = fmaxf(a1, 0.f);
    h3s[2][n] = fmaxf(a2, 0.f); h3s[3][n] = fmaxf(a3, 0.f);
  }
  __syncthreads();

  // L4: z[r][32]; thread (kg = t>>5 in 0..7, n = t&31) covers k = kg*128..+127
  {
    int n = t & 31, kg = t >> 5;
    float a0 = 0.f, a1 = 0.f, a2 = 0.f, a3 = 0.f;
    for (int k = kg*128; k < kg*128 + 128; ++k) {
      float wv = W4[k*32 + n];
      a0 += h3s[0][k]*wv; a1 += h3s[1][k]*wv;
      a2 += h3s[2][k]*wv; a3 += h3s[3][k]*wv;
    }
    part[kg][0*32 + n] = a0; part[kg][1*32 + n] = a1;
    part[kg][2*32 + n] = a2; part[kg][3*32 + n] = a3;
  }
  __syncthreads();
  if (t < 128) {
    float s = 0.f;
    #pragma unroll
    for (int kg = 0; kg < 8; ++kg) s += part[kg][t];
    zs[t >> 5][t & 31] = fmaxf(s + b4[t & 31], 0.f);
  }
  __syncthreads();

  // L5: d1[r][1024] fp8 x2^6; wave w covers n = w*256..+255, 4 rows per thread
  #pragma unroll
  for (int jj = 0; jj < 4; ++jj) {
    int n = w*256 + jj*64 + l;
    float a0 = bd1[n], a1 = a0, a2 = a0, a3 = a0;
    #pragma unroll
    for (int k = 0; k < 32; ++k) {
      float wv = Wd1[k*1024 + n];
      a0 += zs[0][k]*wv; a1 += zs[1][k]*wv;
      a2 += zs[2][k]*wv; a3 += zs[3][k]*wv;
    }
    d1[(m0 + 0)*1024 + n] = f2fp8(fmaxf(a0, 0.f) * ACT_SCALE);
    d1[(m0 + 1)*1024 + n] = f2fp8(fmaxf(a1, 0.f) * ACT_SCALE);
    d1[(m0 + 2)*1024 + n] = f2fp8(fmaxf(a2, 0.f) * ACT_SCALE);
    d1[(m0 + 3)*1024 + n] = f2fp8(fmaxf(a3, 0.f) * ACT_SCALE);
  }
}

extern "C" void kernel_launch(void* const* d_in, const int* in_sizes, int n_in,
                              void* d_out, int out_size, void* d_ws, size_t ws_size,
                              hipStream_t stream)
{
  (void)in_sizes; (void)n_in; (void)out_size; (void)ws_size;
  const float* x   = (const float*)d_in[0];
  const float* C1  = (const float*)d_in[1];
  const float* W1  = (const float*)d_in[2];
  const float* b1  = (const float*)d_in[3];
  const float* C2  = (const float*)d_in[4];
  const float* W2  = (const float*)d_in[5];
  const float* b2  = (const float*)d_in[6];
  const float* W3  = (const float*)d_in[7];
  const float* b3  = (const float*)d_in[8];
  const float* W4  = (const float*)d_in[9];
  const float* b4  = (const float*)d_in[10];
  const float* Wd1 = (const float*)d_in[11];
  const float* bd1 = (const float*)d_in[12];
  const float* Wd2 = (const float*)d_in[13];
  const float* bd2 = (const float*)d_in[14];
  const float* Wd3 = (const float*)d_in[15];
  const float* bd3 = (const float*)d_in[16];
  float* out = (float*)d_out;

  char* ws = (char*)d_ws;
  size_t off = 0;
  auto alloc = [&](size_t bytes) -> void* {
    void* p = ws + off; off += (bytes + 255) & ~(size_t)255; return p;
  };
  unsigned char* Wt2 = (unsigned char*)alloc((size_t)2048*1024);   // Wd2^T fp8 x16
  unsigned char* Wt3 = (unsigned char*)alloc((size_t)4096*2048);   // Wd3^T fp8 x16
  unsigned*      pk  = (unsigned*)     alloc((size_t)196*21*4);    // packed sparse W1C1
  unsigned short* h1 = (unsigned short*)alloc((size_t)8192*256*2); // bf16
  unsigned char*  d1 = (unsigned char*) alloc((size_t)8192*1024);  // fp8 x2^6
  unsigned char*  d2 = (unsigned char*) alloc((size_t)8192*2048);  // fp8 x2^6

  // prep
  build_sparse<<<dim3(196), 256, 0, stream>>>(C1, W1, pk);
  transpose_fp8<<<dim3(1024/32, 2048/32), 256, 0, stream>>>(Wd2, Wt2, 1024, 2048);
  transpose_fp8<<<dim3(2048/32, 4096/32), 256, 0, stream>>>(Wd3, Wt3, 2048, 4096);

  // L1: h1 = relu(x @ (W1*C1) + b1) — sparse gather, x read once
  layer1_sparse<<<dim3(8192/2), 256, 0, stream>>>(x, pk, b1, h1);
  // L2..L5 fused
  layer2345<<<dim3(8192/4), 256, 0, stream>>>(h1, W2, C2, b2, W3, b3, W4, b4,
                                              Wd1, bd1, d1);
  // L6: d2 = relu(d1 @ Wd2 + bd2)  M=8192 N=2048 K=1024  (MX-fp8, 128x256)
  gemm_fp8<0><<<dim3(8192/128, 2048/256), 256, 0, stream>>>(
      d1, Wt2, bd2, d2, 1024, 2048);
  // L7: out = sigmoid(d2 @ Wd3 + bd3)  M=8192 N=4096 K=2048  (MX-fp8, 128x256)
  gemm_fp8<1><<<dim3(8192/128, 4096/256), 256, 0, stream>>>(
      d2, Wt3, bd3, out, 2048, 4096);
}